// Round 2
// baseline (1675.832 us; speedup 1.0000x reference)
//
#include <hip/hip_runtime.h>

#define N_NODES  50000
#define N_EDGES  800000
#define DIM      128
#define N_GRAPHS 256
#define N_CLASSES 16
#define N_LAYERS 5
#define BN_EPS   1e-5f

// ---------------- CSR / histogram build ----------------

__global__ void deg_kernel(const int* __restrict__ dst, int* __restrict__ deg, int e_count) {
    int e = blockIdx.x * blockDim.x + threadIdx.x;
    if (e < e_count) atomicAdd(&deg[dst[e]], 1);
}

__global__ void scan_kernel(const int* __restrict__ in, int* __restrict__ outp,
                            int* __restrict__ cursor, int n) {
    __shared__ int tmp[1024];
    __shared__ int carry;
    int tid = threadIdx.x;
    if (tid == 0) carry = 0;
    __syncthreads();
    for (int base = 0; base < n; base += 1024) {
        int i = base + tid;
        int v = (i < n) ? in[i] : 0;
        tmp[tid] = v;
        __syncthreads();
        for (int off = 1; off < 1024; off <<= 1) {
            int t = (tid >= off) ? tmp[tid - off] : 0;
            __syncthreads();
            tmp[tid] += t;
            __syncthreads();
        }
        int excl = carry + tmp[tid] - v;
        if (i < n) {
            outp[i] = excl;
            if (cursor) cursor[i] = excl;
        }
        __syncthreads();
        if (tid == 0) carry += tmp[1023];
        __syncthreads();
    }
    if (tid == 0) outp[n] = carry;
}

__global__ void fill_csr_kernel(const int* __restrict__ src, const int* __restrict__ dst,
                                int* __restrict__ cursor, int* __restrict__ csr, int e_count) {
    int e = blockIdx.x * blockDim.x + threadIdx.x;
    if (e < e_count) {
        int d = dst[e];
        int p = atomicAdd(&cursor[d], 1);
        csr[p] = src[e];
    }
}

__global__ void gcount_kernel(const int* __restrict__ gid, int* __restrict__ cnt, int n) {
    int i = blockIdx.x * blockDim.x + threadIdx.x;
    if (i < n) atomicAdd(&cnt[gid[i]], 1);
}

// ---------------- SpMM: pooled = sum_{src in N(dst)} h[src] + (1+eps)*h[dst] ----------------
// One wave (64 lanes) per destination node; lane handles 2 columns (float2).

__global__ __launch_bounds__(256) void spmm_kernel(
    const float* __restrict__ h, const int* __restrict__ rowptr,
    const int* __restrict__ csr, const float* __restrict__ epsArr, int l,
    float* __restrict__ outp)
{
    int node = blockIdx.x * 4 + (threadIdx.x >> 6);
    if (node >= N_NODES) return;
    int lane = threadIdx.x & 63;
    int beg = rowptr[node], end = rowptr[node + 1];
    const float2* h2 = (const float2*)h;
    float2 acc = make_float2(0.f, 0.f);
    for (int e = beg; e < end; ++e) {
        int s = csr[e];
        float2 v = h2[(size_t)s * 64 + lane];
        acc.x += v.x; acc.y += v.y;
    }
    float ep = 1.0f + epsArr[l];
    float2 hv = h2[(size_t)node * 64 + lane];
    acc.x += ep * hv.x; acc.y += ep * hv.y;
    ((float2*)outp)[(size_t)node * 64 + lane] = acc;
}

// ---------------- GEMM (Z = A @ W, no bias: bias cancels in BN) + column stats ----------------
// 64-row tile per block, 256 threads; thread = 8 rows x 4 cols.

#define GEMM_BM 64

__global__ __launch_bounds__(256) void gemm_stats_kernel(
    const float* __restrict__ A, const float* __restrict__ W,
    float* __restrict__ Z, float* __restrict__ colsum, float* __restrict__ colsumsq,
    int nrows)
{
    __shared__ float As[GEMM_BM][DIM];
    int tid = threadIdx.x;
    int row0 = blockIdx.x * GEMM_BM;

    // stage A tile (zero-pad past nrows)
    {
        const float4* A4 = (const float4*)(A + (size_t)row0 * DIM);
        float4* As4 = (float4*)&As[0][0];
        int valid = nrows - row0; if (valid > GEMM_BM) valid = GEMM_BM;
        int limit4 = valid * (DIM / 4);
        for (int i = tid; i < GEMM_BM * (DIM / 4); i += 256) {
            float4 v = make_float4(0.f, 0.f, 0.f, 0.f);
            if (i < limit4) v = A4[i];
            As4[i] = v;
        }
    }
    __syncthreads();

    int tx = tid & 31;   // column group: cols 4*tx .. 4*tx+3
    int ty = tid >> 5;   // row group:   rows ty*8 .. ty*8+7
    int c0 = tx * 4;

    float acc[8][4];
#pragma unroll
    for (int j = 0; j < 8; ++j)
#pragma unroll
        for (int cc = 0; cc < 4; ++cc) acc[j][cc] = 0.f;

    const float4* Wr = (const float4*)W;  // W[k][c] row-major, float4 granularity
#pragma unroll 2
    for (int k = 0; k < DIM; k += 4) {
        float w[4][4];
#pragma unroll
        for (int i = 0; i < 4; ++i) {
            float4 wv = Wr[(k + i) * (DIM / 4) + tx];
            w[i][0] = wv.x; w[i][1] = wv.y; w[i][2] = wv.z; w[i][3] = wv.w;
        }
#pragma unroll
        for (int j = 0; j < 8; ++j) {
            float4 av = *(const float4*)&As[ty * 8 + j][k];
            float a[4] = {av.x, av.y, av.z, av.w};
#pragma unroll
            for (int i = 0; i < 4; ++i)
#pragma unroll
                for (int cc = 0; cc < 4; ++cc)
                    acc[j][cc] = fmaf(a[i], w[i][cc], acc[j][cc]);
        }
    }

    // store Z
#pragma unroll
    for (int j = 0; j < 8; ++j) {
        int row = row0 + ty * 8 + j;
        if (row < nrows) {
            *(float4*)&Z[(size_t)row * DIM + c0] =
                make_float4(acc[j][0], acc[j][1], acc[j][2], acc[j][3]);
        }
    }

    // block-level column stats -> one atomic per column per block
    __syncthreads();   // done reading As; reuse as reduction scratch
    float* red = &As[0][0];  // layout: [8][256] (sum at +c, sumsq at +128+c)
    float ssum[4], ssq[4];
#pragma unroll
    for (int cc = 0; cc < 4; ++cc) { ssum[cc] = 0.f; ssq[cc] = 0.f; }
#pragma unroll
    for (int j = 0; j < 8; ++j)
#pragma unroll
        for (int cc = 0; cc < 4; ++cc) {
            float v = acc[j][cc];
            ssum[cc] += v; ssq[cc] += v * v;
        }
#pragma unroll
    for (int cc = 0; cc < 4; ++cc) {
        red[ty * 256 + (c0 + cc)]       = ssum[cc];
        red[ty * 256 + 128 + (c0 + cc)] = ssq[cc];
    }
    __syncthreads();
    if (ty == 0) {
#pragma unroll
        for (int cc = 0; cc < 4; ++cc) {
            int c = c0 + cc;
            float ts = 0.f, tq = 0.f;
#pragma unroll
            for (int r = 0; r < 8; ++r) { ts += red[r * 256 + c]; tq += red[r * 256 + 128 + c]; }
            atomicAdd(&colsum[c], ts);
            atomicAdd(&colsumsq[c], tq);
        }
    }
}

// ---------------- BN (training-mode, biased var) + ReLU, in place ----------------

__global__ __launch_bounds__(256) void bnrelu_kernel(
    float* __restrict__ Z, const float* __restrict__ colsum,
    const float* __restrict__ colsumsq, const float* __restrict__ g,
    const float* __restrict__ beta)
{
    const float invN = 1.0f / (float)N_NODES;
    int tid0 = blockIdx.x * blockDim.x + threadIdx.x;
    int cg = tid0 & 31;            // stays constant across grid-stride (stride % 32 == 0)
    float a[4], sh[4];
#pragma unroll
    for (int cc = 0; cc < 4; ++cc) {
        int c = cg * 4 + cc;
        float m = colsum[c] * invN;
        float var = colsumsq[c] * invN - m * m;
        float s = g[c] * rsqrtf(var + BN_EPS);
        a[cc] = s;
        sh[cc] = beta[c] - s * m;
    }
    float4* Z4 = (float4*)Z;
    const int total4 = N_NODES * (DIM / 4);
    int stride = gridDim.x * blockDim.x;
    for (int idx = tid0; idx < total4; idx += stride) {
        float4 z = Z4[idx];
        z.x = fmaxf(fmaf(a[0], z.x, sh[0]), 0.f);
        z.y = fmaxf(fmaf(a[1], z.y, sh[1]), 0.f);
        z.z = fmaxf(fmaf(a[2], z.z, sh[2]), 0.f);
        z.w = fmaxf(fmaf(a[3], z.w, sh[3]), 0.f);
        Z4[idx] = z;
    }
}

// ---------------- graph sum-pool (graph_ids sorted -> contiguous ranges) ----------------

__global__ __launch_bounds__(256) void pool_kernel(
    const float* __restrict__ h, const int* __restrict__ gptr, float* __restrict__ outp)
{
    __shared__ float red[DIM];
    int g = blockIdx.x;
    int c = threadIdx.x & 127;
    int half = threadIdx.x >> 7;
    int beg = gptr[g], end = gptr[g + 1];
    float acc = 0.f;
    for (int n = beg + half; n < end; n += 2) acc += h[(size_t)n * DIM + c];
    if (half == 1) red[c] = acc;
    __syncthreads();
    if (half == 0) outp[(size_t)g * DIM + c] = acc + red[c];
}

// ---------------- final readout: out[g][c] = sum_l pooledH[l][g] @ Wp[l] + bp[l] ----------------

__global__ __launch_bounds__(256) void final_kernel(
    const float* __restrict__ pooledH, const float* __restrict__ Wp,
    const float* __restrict__ bp, float* __restrict__ outp)
{
    int t = blockIdx.x * blockDim.x + threadIdx.x;
    if (t >= N_GRAPHS * N_CLASSES) return;
    int g = t >> 4, c = t & 15;
    float acc = 0.f;
    for (int l = 0; l < N_LAYERS; ++l) {
        const float* ph = pooledH + ((size_t)l * N_GRAPHS + g) * DIM;
        const float* w = Wp + (size_t)l * DIM * N_CLASSES + c;
        float a = 0.f;
        for (int k = 0; k < DIM; ++k) a = fmaf(ph[k], w[k * N_CLASSES], a);
        acc += a + bp[l * N_CLASSES + c];
    }
    outp[t] = acc;
}

// ---------------- host launcher ----------------

extern "C" void kernel_launch(void* const* d_in, const int* in_sizes, int n_in,
                              void* d_out, int out_size, void* d_ws, size_t ws_size,
                              hipStream_t stream) {
    const float* x     = (const float*)d_in[0];
    const float* eps   = (const float*)d_in[1];
    const float* W1    = (const float*)d_in[2];
    const float* g1    = (const float*)d_in[4];
    const float* beta1 = (const float*)d_in[5];
    const float* W2    = (const float*)d_in[6];
    const float* g2    = (const float*)d_in[8];
    const float* beta2 = (const float*)d_in[9];
    const float* Wp    = (const float*)d_in[10];
    const float* bp    = (const float*)d_in[11];
    const int*   esrc  = (const int*)d_in[12];
    const int*   edst  = (const int*)d_in[13];
    const int*   gid   = (const int*)d_in[14];
    float* outp = (float*)d_out;

    char* ws = (char*)d_ws;
    size_t off = 0;
    auto alloc = [&](size_t bytes) {
        char* p = ws + off;
        off = (off + bytes + 255) & ~(size_t)255;
        return p;
    };
    float* S0      = (float*)alloc((size_t)N_NODES * DIM * 4);
    float* S1      = (float*)alloc((size_t)N_NODES * DIM * 4);
    int*   csr     = (int*)alloc((size_t)N_EDGES * 4);
    int*   deg     = (int*)alloc((N_NODES + 1) * 4);
    int*   rowptr  = (int*)alloc((N_NODES + 1) * 4);
    int*   cursor  = (int*)alloc((N_NODES + 1) * 4);
    int*   gcnt    = (int*)alloc(300 * 4);
    int*   growptr = (int*)alloc(300 * 4);
    float* colsum  = (float*)alloc(128 * 4);   // contiguous with colsumsq (both 512B, 256B-aligned)
    float* colsumsq= (float*)alloc(128 * 4);
    float* pooledH = (float*)alloc((size_t)N_LAYERS * N_GRAPHS * DIM * 4);

    hipMemsetAsync(deg, 0, N_NODES * 4, stream);
    hipMemsetAsync(gcnt, 0, 256 * 4, stream);

    deg_kernel<<<(N_EDGES + 255) / 256, 256, 0, stream>>>(edst, deg, N_EDGES);
    scan_kernel<<<1, 1024, 0, stream>>>(deg, rowptr, cursor, N_NODES);
    fill_csr_kernel<<<(N_EDGES + 255) / 256, 256, 0, stream>>>(esrc, edst, cursor, csr, N_EDGES);
    gcount_kernel<<<(N_NODES + 255) / 256, 256, 0, stream>>>(gid, gcnt, N_NODES);
    scan_kernel<<<1, 1024, 0, stream>>>(gcnt, growptr, (int*)nullptr, N_GRAPHS);

    pool_kernel<<<N_GRAPHS, 256, 0, stream>>>(x, growptr, pooledH);

    const float* cur = x;
    float* P = S0;
    float* Z = S1;
    for (int l = 0; l < N_LAYERS - 1; ++l) {
        spmm_kernel<<<(N_NODES + 3) / 4, 256, 0, stream>>>(cur, rowptr, csr, eps, l, P);

        hipMemsetAsync(colsum, 0, 1024, stream);  // covers colsum + colsumsq
        gemm_stats_kernel<<<(N_NODES + GEMM_BM - 1) / GEMM_BM, 256, 0, stream>>>(
            P, W1 + (size_t)l * DIM * DIM, Z, colsum, colsumsq, N_NODES);
        bnrelu_kernel<<<1024, 256, 0, stream>>>(Z, colsum, colsumsq, g1 + l * DIM, beta1 + l * DIM);

        hipMemsetAsync(colsum, 0, 1024, stream);
        gemm_stats_kernel<<<(N_NODES + GEMM_BM - 1) / GEMM_BM, 256, 0, stream>>>(
            Z, W2 + (size_t)l * DIM * DIM, P, colsum, colsumsq, N_NODES);
        bnrelu_kernel<<<1024, 256, 0, stream>>>(P, colsum, colsumsq, g2 + l * DIM, beta2 + l * DIM);

        pool_kernel<<<N_GRAPHS, 256, 0, stream>>>(P, growptr, pooledH + (size_t)(l + 1) * N_GRAPHS * DIM);

        cur = P;
        float* t = P; P = Z; Z = t;
    }

    final_kernel<<<(N_GRAPHS * N_CLASSES + 255) / 256, 256, 0, stream>>>(pooledH, Wp, bp, outp);
}

// Round 3
// 1095.832 us; speedup vs baseline: 1.5293x; 1.5293x over previous
//
#include <hip/hip_runtime.h>

#define N_NODES  50000
#define N_EDGES  800000
#define DIM      128
#define N_GRAPHS 256
#define N_CLASSES 16
#define N_LAYERS 5
#define BN_EPS   1e-5f

typedef short bf16x8 __attribute__((ext_vector_type(8)));
typedef float f32x4  __attribute__((ext_vector_type(4)));

__device__ __forceinline__ float bf2f(unsigned short u) {
    unsigned int x = ((unsigned int)u) << 16;
    return __builtin_bit_cast(float, x);
}
__device__ __forceinline__ unsigned short f2bf(float f) {
    unsigned int x = __builtin_bit_cast(unsigned int, f);
    x += 0x7fffu + ((x >> 16) & 1u);   // RNE
    return (unsigned short)(x >> 16);
}

// ---------------- CSR / histogram build ----------------

__global__ void deg_kernel(const int* __restrict__ dst, int* __restrict__ deg, int e_count) {
    int e = blockIdx.x * blockDim.x + threadIdx.x;
    if (e < e_count) atomicAdd(&deg[dst[e]], 1);
}

__global__ void scan_kernel(const int* __restrict__ in, int* __restrict__ outp,
                            int* __restrict__ cursor, int n) {
    __shared__ int tmp[1024];
    __shared__ int carry;
    int tid = threadIdx.x;
    if (tid == 0) carry = 0;
    __syncthreads();
    for (int base = 0; base < n; base += 1024) {
        int i = base + tid;
        int v = (i < n) ? in[i] : 0;
        tmp[tid] = v;
        __syncthreads();
        for (int off = 1; off < 1024; off <<= 1) {
            int t = (tid >= off) ? tmp[tid - off] : 0;
            __syncthreads();
            tmp[tid] += t;
            __syncthreads();
        }
        int excl = carry + tmp[tid] - v;
        if (i < n) {
            outp[i] = excl;
            if (cursor) cursor[i] = excl;
        }
        __syncthreads();
        if (tid == 0) carry += tmp[1023];
        __syncthreads();
    }
    if (tid == 0) outp[n] = carry;
}

__global__ void fill_csr_kernel(const int* __restrict__ src, const int* __restrict__ dst,
                                int* __restrict__ cursor, int* __restrict__ csr, int e_count) {
    int e = blockIdx.x * blockDim.x + threadIdx.x;
    if (e < e_count) {
        int d = dst[e];
        int p = atomicAdd(&cursor[d], 1);
        csr[p] = src[e];
    }
}

__global__ void gcount_kernel(const int* __restrict__ gid, int* __restrict__ cnt, int n) {
    int i = blockIdx.x * blockDim.x + threadIdx.x;
    if (i < n) atomicAdd(&cnt[gid[i]], 1);
}

// ---------------- conversions ----------------

__global__ void f2b_kernel(const float* __restrict__ in, unsigned short* __restrict__ outp, int n) {
    int i = blockIdx.x * blockDim.x + threadIdx.x;
    if (i < n) outp[i] = f2bf(in[i]);
}

// W[k][c] fp32 -> Wt[c][k] bf16 (per matrix), nmat matrices of 128x128
__global__ void wconv_kernel(const float* __restrict__ W, unsigned short* __restrict__ Wt, int nmat) {
    int t = blockIdx.x * blockDim.x + threadIdx.x;
    if (t >= nmat * DIM * DIM) return;
    int m = t >> 14;
    int rem = t & 16383;
    int k = rem >> 7;
    int c = rem & 127;
    Wt[((size_t)m << 14) + (size_t)c * DIM + k] = f2bf(W[t]);
}

// ---------------- SpMM (bf16): pooled = sum_{src in N(dst)} h[src] + (1+eps)*h[dst] ----------------
// One wave per destination node; lane handles 2 columns (one dword = bf16x2).

__global__ __launch_bounds__(256) void spmm_bf16_kernel(
    const unsigned short* __restrict__ h, const int* __restrict__ rowptr,
    const int* __restrict__ csr, const float* __restrict__ epsArr, int l,
    unsigned short* __restrict__ outp)
{
    int node = blockIdx.x * 4 + (threadIdx.x >> 6);
    if (node >= N_NODES) return;
    int lane = threadIdx.x & 63;
    const unsigned int* h2 = (const unsigned int*)h;
    int beg = rowptr[node], end = rowptr[node + 1];
    float ax = 0.f, ay = 0.f;
    for (int e = beg; e < end; ++e) {
        int s = csr[e];
        unsigned int v = h2[(size_t)s * 64 + lane];
        ax += bf2f((unsigned short)(v & 0xffffu));
        ay += bf2f((unsigned short)(v >> 16));
    }
    float ep = 1.0f + epsArr[l];
    unsigned int hv = h2[(size_t)node * 64 + lane];
    ax += ep * bf2f((unsigned short)(hv & 0xffffu));
    ay += ep * bf2f((unsigned short)(hv >> 16));
    unsigned int o = (unsigned int)f2bf(ax) | ((unsigned int)f2bf(ay) << 16);
    ((unsigned int*)outp)[(size_t)node * 64 + lane] = o;
}

// ---------------- MFMA GEMM (bf16): Z = A @ W  (+ fp32 column stats) ----------------
// A: [nrows][128] bf16 row-major; Wt: [128][128] bf16 = W^T (Wt[c][k]).
// Block: 256 threads = 4 waves, BM=64 rows (16 rows/wave), full 128 cols.
// mfma_f32_16x16x32_bf16: A-frag lane holds A[row=lane&15][k0 + (lane>>4)*8 + j],
// B-frag lane holds W[k0+(lane>>4)*8+j][col=lane&15] = Wt[col][k...] (contiguous),
// C/D: col=lane&15, row=(lane>>4)*4+reg  [verified m89/m91].

#define GEMM_BM 64
#define LDSP 136   // padded row stride (bf16 elems): 272B = 17*16B, breaks 32-way banking

__global__ __launch_bounds__(256) void gemm_bf16_kernel(
    const unsigned short* __restrict__ A, const unsigned short* __restrict__ Wt,
    unsigned short* __restrict__ Z, float* __restrict__ colsum, float* __restrict__ colsumsq,
    int nrows)
{
    __shared__ unsigned short As[GEMM_BM][LDSP];
    __shared__ unsigned short Ws[DIM][LDSP];
    int tid = threadIdx.x;
    int row0 = blockIdx.x * GEMM_BM;

    // stage A tile: 64 rows x 16 chunks(16B) = 1024 chunks
#pragma unroll
    for (int it = 0; it < 4; ++it) {
        int c = tid + it * 256;
        int r = c >> 4, kc = c & 15;
        bf16x8 v = {0, 0, 0, 0, 0, 0, 0, 0};
        if (row0 + r < nrows)
            v = *(const bf16x8*)(A + (size_t)(row0 + r) * DIM + kc * 8);
        *(bf16x8*)&As[r][kc * 8] = v;
    }
    // stage Wt: 128 rows x 16 chunks = 2048 chunks
#pragma unroll
    for (int it = 0; it < 8; ++it) {
        int c = tid + it * 256;
        int r = c >> 4, kc = c & 15;
        *(bf16x8*)&Ws[r][kc * 8] = *(const bf16x8*)(Wt + (size_t)r * DIM + kc * 8);
    }
    __syncthreads();

    int wid = tid >> 6, lane = tid & 63;
    int m0 = wid * 16;
    int lrow = lane & 15;
    int lk = (lane >> 4) * 8;

    f32x4 acc[8];
#pragma unroll
    for (int n = 0; n < 8; ++n) acc[n] = (f32x4){0.f, 0.f, 0.f, 0.f};

#pragma unroll
    for (int kk = 0; kk < 4; ++kk) {
        int k0 = kk * 32;
        bf16x8 a = *(const bf16x8*)&As[m0 + lrow][k0 + lk];
#pragma unroll
        for (int n = 0; n < 8; ++n) {
            bf16x8 b = *(const bf16x8*)&Ws[n * 16 + lrow][k0 + lk];
            acc[n] = __builtin_amdgcn_mfma_f32_16x16x32_bf16(a, b, acc[n], 0, 0, 0);
        }
    }

    // epilogue: store bf16 Z + wave-level column stats
    int r0 = row0 + m0 + (lane >> 4) * 4;
    float sarr[8], qarr[8];
#pragma unroll
    for (int n = 0; n < 8; ++n) {
        int col = n * 16 + lrow;
        float s = 0.f, q = 0.f;
#pragma unroll
        for (int j = 0; j < 4; ++j) {
            float v = acc[n][j];          // pad rows produce exact 0 (As zero-filled)
            int row = r0 + j;
            if (row < nrows) Z[(size_t)row * DIM + col] = f2bf(v);
            s += v; q += v * v;
        }
        s += __shfl_xor(s, 16); q += __shfl_xor(q, 16);
        s += __shfl_xor(s, 32); q += __shfl_xor(q, 32);
        sarr[n] = s; qarr[n] = q;          // all lanes now hold wave total for (n, lrow)
    }

    __syncthreads();                       // done with As/Ws; reuse As as fp32 scratch
    float* red = (float*)&As[0][0];        // [4 waves][256] : sum at +c, sumsq at +128+c
    if (lane < 16) {
#pragma unroll
        for (int n = 0; n < 8; ++n) {
            red[wid * 256 + n * 16 + lrow]       = sarr[n];
            red[wid * 256 + 128 + n * 16 + lrow] = qarr[n];
        }
    }
    __syncthreads();
    if (tid < 128) {
        float ts = red[tid] + red[256 + tid] + red[512 + tid] + red[768 + tid];
        float tq = red[128 + tid] + red[384 + tid] + red[640 + tid] + red[896 + tid];
        atomicAdd(&colsum[tid], ts);
        atomicAdd(&colsumsq[tid], tq);
    }
}

// ---------------- BN (training-mode, biased var) + ReLU, in place on bf16 ----------------

__global__ __launch_bounds__(256) void bnrelu_bf16_kernel(
    unsigned short* __restrict__ Z, const float* __restrict__ colsum,
    const float* __restrict__ colsumsq, const float* __restrict__ g,
    const float* __restrict__ beta)
{
    const float invN = 1.0f / (float)N_NODES;
    int tid0 = blockIdx.x * blockDim.x + threadIdx.x;
    int cg = tid0 & 15;   // 16 bf16x8-chunks per row; stride % 16 == 0 keeps cg invariant
    float a[8], sh[8];
#pragma unroll
    for (int cc = 0; cc < 8; ++cc) {
        int c = cg * 8 + cc;
        float m = colsum[c] * invN;
        float var = colsumsq[c] * invN - m * m;
        float s = g[c] * rsqrtf(var + BN_EPS);
        a[cc] = s;
        sh[cc] = beta[c] - s * m;
    }
    bf16x8* Z8 = (bf16x8*)Z;
    const int total = N_NODES * (DIM / 8);
    int stride = gridDim.x * blockDim.x;
    for (int idx = tid0; idx < total; idx += stride) {
        bf16x8 z = Z8[idx];
        bf16x8 o;
#pragma unroll
        for (int cc = 0; cc < 8; ++cc) {
            float v = bf2f((unsigned short)z[cc]);
            v = fmaxf(fmaf(a[cc], v, sh[cc]), 0.f);
            o[cc] = (short)f2bf(v);
        }
        Z8[idx] = o;
    }
}

// ---------------- graph sum-pool (fp32 input: layer 0 only) ----------------

__global__ __launch_bounds__(256) void pool_kernel(
    const float* __restrict__ h, const int* __restrict__ gptr, float* __restrict__ outp)
{
    __shared__ float red[DIM];
    int g = blockIdx.x;
    int c = threadIdx.x & 127;
    int half = threadIdx.x >> 7;
    int beg = gptr[g], end = gptr[g + 1];
    float acc = 0.f;
    for (int n = beg + half; n < end; n += 2) acc += h[(size_t)n * DIM + c];
    if (half == 1) red[c] = acc;
    __syncthreads();
    if (half == 0) outp[(size_t)g * DIM + c] = acc + red[c];
}

// ---------------- graph sum-pool (bf16 input) ----------------

__global__ __launch_bounds__(256) void pool_bf16_kernel(
    const unsigned short* __restrict__ h, const int* __restrict__ gptr, float* __restrict__ outp)
{
    __shared__ float red[DIM];
    int g = blockIdx.x;
    int c = threadIdx.x & 127;
    int half = threadIdx.x >> 7;
    int beg = gptr[g], end = gptr[g + 1];
    float acc = 0.f;
    for (int n = beg + half; n < end; n += 2) acc += bf2f(h[(size_t)n * DIM + c]);
    if (half == 1) red[c] = acc;
    __syncthreads();
    if (half == 0) outp[(size_t)g * DIM + c] = acc + red[c];
}

// ---------------- final readout: out[g][c] = sum_l pooledH[l][g] @ Wp[l] + bp[l] ----------------

__global__ __launch_bounds__(256) void final_kernel(
    const float* __restrict__ pooledH, const float* __restrict__ Wp,
    const float* __restrict__ bp, float* __restrict__ outp)
{
    int t = blockIdx.x * blockDim.x + threadIdx.x;
    if (t >= N_GRAPHS * N_CLASSES) return;
    int g = t >> 4, c = t & 15;
    float acc = 0.f;
    for (int l = 0; l < N_LAYERS; ++l) {
        const float* ph = pooledH + ((size_t)l * N_GRAPHS + g) * DIM;
        const float* w = Wp + (size_t)l * DIM * N_CLASSES + c;
        float a = 0.f;
        for (int k = 0; k < DIM; ++k) a = fmaf(ph[k], w[k * N_CLASSES], a);
        acc += a + bp[l * N_CLASSES + c];
    }
    outp[t] = acc;
}

// ---------------- host launcher ----------------

extern "C" void kernel_launch(void* const* d_in, const int* in_sizes, int n_in,
                              void* d_out, int out_size, void* d_ws, size_t ws_size,
                              hipStream_t stream) {
    const float* x     = (const float*)d_in[0];
    const float* eps   = (const float*)d_in[1];
    const float* W1    = (const float*)d_in[2];
    const float* g1    = (const float*)d_in[4];
    const float* beta1 = (const float*)d_in[5];
    const float* W2    = (const float*)d_in[6];
    const float* g2    = (const float*)d_in[8];
    const float* beta2 = (const float*)d_in[9];
    const float* Wp    = (const float*)d_in[10];
    const float* bp    = (const float*)d_in[11];
    const int*   esrc  = (const int*)d_in[12];
    const int*   edst  = (const int*)d_in[13];
    const int*   gid   = (const int*)d_in[14];
    float* outp = (float*)d_out;

    char* ws = (char*)d_ws;
    size_t off = 0;
    auto alloc = [&](size_t bytes) {
        char* p = ws + off;
        off = (off + bytes + 255) & ~(size_t)255;
        return p;
    };
    unsigned short* xb  = (unsigned short*)alloc((size_t)N_NODES * DIM * 2);
    unsigned short* B0  = (unsigned short*)alloc((size_t)N_NODES * DIM * 2);  // pooled
    unsigned short* B1  = (unsigned short*)alloc((size_t)N_NODES * DIM * 2);  // h alternate
    unsigned short* ZB  = (unsigned short*)alloc((size_t)N_NODES * DIM * 2);  // Z
    unsigned short* Wt1 = (unsigned short*)alloc((size_t)(N_LAYERS - 1) * DIM * DIM * 2);
    unsigned short* Wt2 = (unsigned short*)alloc((size_t)(N_LAYERS - 1) * DIM * DIM * 2);
    int*   csr     = (int*)alloc((size_t)N_EDGES * 4);
    int*   deg     = (int*)alloc((N_NODES + 1) * 4);
    int*   rowptr  = (int*)alloc((N_NODES + 1) * 4);
    int*   cursor  = (int*)alloc((N_NODES + 1) * 4);
    int*   gcnt    = (int*)alloc(300 * 4);
    int*   growptr = (int*)alloc(300 * 4);
    float* colsum  = (float*)alloc(128 * 4);   // contiguous with colsumsq
    float* colsumsq= (float*)alloc(128 * 4);
    float* pooledH = (float*)alloc((size_t)N_LAYERS * N_GRAPHS * DIM * 4);

    hipMemsetAsync(deg, 0, N_NODES * 4, stream);
    hipMemsetAsync(gcnt, 0, 256 * 4, stream);

    deg_kernel<<<(N_EDGES + 255) / 256, 256, 0, stream>>>(edst, deg, N_EDGES);
    scan_kernel<<<1, 1024, 0, stream>>>(deg, rowptr, cursor, N_NODES);
    fill_csr_kernel<<<(N_EDGES + 255) / 256, 256, 0, stream>>>(esrc, edst, cursor, csr, N_EDGES);
    gcount_kernel<<<(N_NODES + 255) / 256, 256, 0, stream>>>(gid, gcnt, N_NODES);
    scan_kernel<<<1, 1024, 0, stream>>>(gcnt, growptr, (int*)nullptr, N_GRAPHS);

    // conversions
    f2b_kernel<<<(N_NODES * DIM + 255) / 256, 256, 0, stream>>>(x, xb, N_NODES * DIM);
    wconv_kernel<<<((N_LAYERS - 1) * DIM * DIM + 255) / 256, 256, 0, stream>>>(W1, Wt1, N_LAYERS - 1);
    wconv_kernel<<<((N_LAYERS - 1) * DIM * DIM + 255) / 256, 256, 0, stream>>>(W2, Wt2, N_LAYERS - 1);

    pool_kernel<<<N_GRAPHS, 256, 0, stream>>>(x, growptr, pooledH);   // layer 0 (exact fp32)

    const int gemm_grid = (N_NODES + GEMM_BM - 1) / GEMM_BM;
    unsigned short* hb = xb;   // current h (bf16)
    unsigned short* nb = B1;   // next h
    for (int l = 0; l < N_LAYERS - 1; ++l) {
        spmm_bf16_kernel<<<(N_NODES + 3) / 4, 256, 0, stream>>>(hb, rowptr, csr, eps, l, B0);

        hipMemsetAsync(colsum, 0, 1024, stream);  // colsum + colsumsq
        gemm_bf16_kernel<<<gemm_grid, 256, 0, stream>>>(
            B0, Wt1 + (size_t)l * DIM * DIM, ZB, colsum, colsumsq, N_NODES);
        bnrelu_bf16_kernel<<<1024, 256, 0, stream>>>(ZB, colsum, colsumsq, g1 + l * DIM, beta1 + l * DIM);

        hipMemsetAsync(colsum, 0, 1024, stream);
        gemm_bf16_kernel<<<gemm_grid, 256, 0, stream>>>(
            ZB, Wt2 + (size_t)l * DIM * DIM, nb, colsum, colsumsq, N_NODES);
        bnrelu_bf16_kernel<<<1024, 256, 0, stream>>>(nb, colsum, colsumsq, g2 + l * DIM, beta2 + l * DIM);

        pool_bf16_kernel<<<N_GRAPHS, 256, 0, stream>>>(nb, growptr, pooledH + (size_t)(l + 1) * N_GRAPHS * DIM);

        unsigned short* t = hb; hb = nb; nb = t;   // rotate h buffers (xb reusable after layer 0)
    }

    final_kernel<<<(N_GRAPHS * N_CLASSES + 255) / 256, 256, 0, stream>>>(pooledH, Wp, bp, outp);
}

// Round 4
// 869.728 us; speedup vs baseline: 1.9268x; 1.2600x over previous
//
#include <hip/hip_runtime.h>

#define N_NODES  50000
#define N_EDGES  800000
#define DIM      128
#define N_GRAPHS 256
#define N_CLASSES 16
#define N_LAYERS 5
#define BN_EPS   1e-5f

#define GEMM_BM 64
#define LDSP 136   // padded LDS row stride (bf16 elems): 272B breaks power-of-2 banking

typedef short bf16x8 __attribute__((ext_vector_type(8)));
typedef float f32x4  __attribute__((ext_vector_type(4)));

__device__ __forceinline__ float bf2f(unsigned short u) {
    unsigned int x = ((unsigned int)u) << 16;
    return __builtin_bit_cast(float, x);
}
__device__ __forceinline__ unsigned short f2bf(float f) {
    unsigned int x = __builtin_bit_cast(unsigned int, f);
    x += 0x7fffu + ((x >> 16) & 1u);   // RNE
    return (unsigned short)(x >> 16);
}
__device__ __forceinline__ float lo16(unsigned int v) { return bf2f((unsigned short)(v & 0xffffu)); }
__device__ __forceinline__ float hi16(unsigned int v) { return bf2f((unsigned short)(v >> 16)); }
__device__ __forceinline__ unsigned int pack16(float a, float b) {
    return (unsigned int)f2bf(a) | ((unsigned int)f2bf(b) << 16);
}

// ---------------- CSR / histogram build ----------------

__global__ void deg_kernel(const int* __restrict__ dst, int* __restrict__ deg, int e_count) {
    int e = blockIdx.x * blockDim.x + threadIdx.x;
    if (e < e_count) atomicAdd(&deg[dst[e]], 1);
}

__global__ void fill_csr_kernel(const int* __restrict__ src, const int* __restrict__ dst,
                                int* __restrict__ cursor, int* __restrict__ csr, int e_count) {
    int e = blockIdx.x * blockDim.x + threadIdx.x;
    if (e < e_count) {
        int d = dst[e];
        int p = atomicAdd(&cursor[d], 1);
        csr[p] = src[e];
    }
}

__global__ void gcount_kernel(const int* __restrict__ gid, int* __restrict__ cnt, int n) {
    int i = blockIdx.x * blockDim.x + threadIdx.x;
    if (i < n) atomicAdd(&cnt[gid[i]], 1);
}

// ---------------- fast 3-phase exclusive scan (replaces 92us single-block scan) ----------------

__global__ __launch_bounds__(1024) void scan_part_kernel(const int* __restrict__ in,
                                                         int* __restrict__ part, int n) {
    __shared__ int red[16];
    int tid = threadIdx.x;
    int i = blockIdx.x * 1024 + tid;
    int v = (i < n) ? in[i] : 0;
#pragma unroll
    for (int d = 1; d < 64; d <<= 1) v += __shfl_xor(v, d, 64);
    int lane = tid & 63, w = tid >> 6;
    if (lane == 0) red[w] = v;
    __syncthreads();
    if (tid == 0) {
        int s = 0;
#pragma unroll
        for (int k = 0; k < 16; ++k) s += red[k];
        part[blockIdx.x] = s;
    }
}

// single wave: exclusive-scan <=64 partials in place; writes grand total to total_out[total_idx]
__global__ void scan_mid_kernel(int* __restrict__ part, int nb,
                                int* __restrict__ total_out, int total_idx) {
    int lane = threadIdx.x;
    int orig = (lane < nb) ? part[lane] : 0;
    int v = orig;
#pragma unroll
    for (int d = 1; d < 64; d <<= 1) {
        int t = __shfl_up(v, d, 64);
        if (lane >= d) v += t;
    }
    if (lane < nb) part[lane] = v - orig;
    if (lane == 63) total_out[total_idx] = v;
}

__global__ __launch_bounds__(1024) void scan_final_kernel(const int* __restrict__ in,
                                                          const int* __restrict__ part,
                                                          int* __restrict__ rowptr,
                                                          int* __restrict__ cursor, int n) {
    __shared__ int woff[16];
    int tid = threadIdx.x;
    int i = blockIdx.x * 1024 + tid;
    int v = (i < n) ? in[i] : 0;
    int lane = tid & 63, w = tid >> 6;
    int x = v;
#pragma unroll
    for (int d = 1; d < 64; d <<= 1) {
        int t = __shfl_up(x, d, 64);
        if (lane >= d) x += t;
    }
    if (lane == 63) woff[w] = x;
    __syncthreads();
    if (tid == 0) {
        int s = 0;
#pragma unroll
        for (int k = 0; k < 16; ++k) { int t = woff[k]; woff[k] = s; s += t; }
    }
    __syncthreads();
    int excl = part[blockIdx.x] + woff[w] + x - v;
    if (i < n) { rowptr[i] = excl; cursor[i] = excl; }
}

// one-block scan for <=1024 elems (graph histogram); writes outp[n] = total
__global__ __launch_bounds__(1024) void scan_small_kernel(const int* __restrict__ in,
                                                          int* __restrict__ outp, int n) {
    __shared__ int wsum[16], woff[16];
    int tid = threadIdx.x;
    int v = (tid < n) ? in[tid] : 0;
    int lane = tid & 63, w = tid >> 6;
    int x = v;
#pragma unroll
    for (int d = 1; d < 64; d <<= 1) {
        int t = __shfl_up(x, d, 64);
        if (lane >= d) x += t;
    }
    if (lane == 63) wsum[w] = x;
    __syncthreads();
    if (tid == 0) {
        int s = 0;
#pragma unroll
        for (int k = 0; k < 16; ++k) { woff[k] = s; s += wsum[k]; }
        wsum[15] = s;   // grand total (after offsets captured)
    }
    __syncthreads();
    if (tid < n) outp[tid] = woff[w] + x - v;
    if (tid == 0) outp[n] = wsum[15];
}

// ---------------- conversions ----------------

__global__ void f2b_kernel(const float* __restrict__ in, unsigned short* __restrict__ outp, int n4) {
    int i = blockIdx.x * blockDim.x + threadIdx.x;
    if (i >= n4) return;
    float4 v = ((const float4*)in)[i];
    unsigned int a = pack16(v.x, v.y);
    unsigned int b = pack16(v.z, v.w);
    ((uint2*)outp)[i] = make_uint2(a, b);
}

// W[k][c] fp32 -> Wt[c][k] bf16 (nmat matrices of 128x128)
__global__ void wconv_kernel(const float* __restrict__ W, unsigned short* __restrict__ Wt, int nmat) {
    int t = blockIdx.x * blockDim.x + threadIdx.x;
    if (t >= nmat * DIM * DIM) return;
    int m = t >> 14;
    int rem = t & 16383;
    int k = rem >> 7;
    int c = rem & 127;
    Wt[((size_t)m << 14) + (size_t)c * DIM + k] = f2bf(W[t]);
}

// ---------------- shared GEMM core: MFMA over 64x128 LDS A-tile, B-frags from L2 ----------------
// A: As[64][LDSP] bf16; Wt[c][k] = W^T bf16 (L2-resident, 32KB).
// mfma_f32_16x16x32_bf16 layouts verified (round 3 passed with asymmetric weights):
//  A-frag: lane holds A[lane&15][k0+(lane>>4)*8+j]; B-frag: lane holds Wt[col=lane&15][k...];
//  C/D: col=lane&15, row=(lane>>4)*4+reg.

__device__ __forceinline__ void gemm_core(
    unsigned short (*As)[LDSP], const unsigned short* __restrict__ Wt,
    unsigned short* __restrict__ Z, float* __restrict__ colsum, float* __restrict__ colsumsq,
    int nrows, int row0, int tid)
{
    int wid = tid >> 6, lane = tid & 63;
    int m0 = wid * 16;
    int lrow = lane & 15;
    int lk = (lane >> 4) * 8;

    f32x4 acc[8];
#pragma unroll
    for (int n = 0; n < 8; ++n) acc[n] = (f32x4){0.f, 0.f, 0.f, 0.f};

#pragma unroll
    for (int kk = 0; kk < 4; ++kk) {
        int k0 = kk * 32;
        bf16x8 a = *(const bf16x8*)&As[m0 + lrow][k0 + lk];
#pragma unroll
        for (int n = 0; n < 8; ++n) {
            bf16x8 b = *(const bf16x8*)(Wt + (size_t)(n * 16 + lrow) * DIM + k0 + lk);
            acc[n] = __builtin_amdgcn_mfma_f32_16x16x32_bf16(a, b, acc[n], 0, 0, 0);
        }
    }

    // epilogue: bf16 Z store + fp32 column stats (pad rows contribute exact 0)
    int r0 = row0 + m0 + (lane >> 4) * 4;
    float sarr[8], qarr[8];
#pragma unroll
    for (int n = 0; n < 8; ++n) {
        int col = n * 16 + lrow;
        float s = 0.f, q = 0.f;
#pragma unroll
        for (int j = 0; j < 4; ++j) {
            float v = acc[n][j];
            int row = r0 + j;
            if (row < nrows) Z[(size_t)row * DIM + col] = f2bf(v);
            s += v; q += v * v;
        }
        s += __shfl_xor(s, 16); q += __shfl_xor(q, 16);
        s += __shfl_xor(s, 32); q += __shfl_xor(q, 32);
        sarr[n] = s; qarr[n] = q;
    }

    __syncthreads();                   // done with As; reuse as fp32 scratch (aligned(16))
    float* red = (float*)&As[0][0];    // [4 waves][256]: sum at +c, sumsq at +128+c
    if (lane < 16) {
#pragma unroll
        for (int n = 0; n < 8; ++n) {
            red[wid * 256 + n * 16 + lrow]       = sarr[n];
            red[wid * 256 + 128 + n * 16 + lrow] = qarr[n];
        }
    }
    __syncthreads();
    if (tid < 128) {
        float ts = red[tid] + red[256 + tid] + red[512 + tid] + red[768 + tid];
        float tq = red[128 + tid] + red[384 + tid] + red[640 + tid] + red[896 + tid];
        atomicAdd(&colsum[tid], ts);
        atomicAdd(&colsumsq[tid], tq);
    }
}

// ---------------- gemmA: fused SpMM-gather staging + GEMM1 + stats ----------------
// Wave w gathers nodes row0+w*16..+15 (lane = 2 cols); P tile lives only in LDS.

__global__ __launch_bounds__(256) void gemmA_kernel(
    const unsigned short* __restrict__ h, const int* __restrict__ rowptr,
    const int* __restrict__ csr, const float* __restrict__ epsArr, int l,
    const unsigned short* __restrict__ Wt, unsigned short* __restrict__ Z,
    float* __restrict__ stats, int nrows)
{
    __shared__ __attribute__((aligned(16))) unsigned short As[GEMM_BM][LDSP];
    int tid = threadIdx.x;
    int row0 = blockIdx.x * GEMM_BM;
    int wid = tid >> 6, lane = tid & 63;
    float ep = 1.0f + epsArr[l];
    const unsigned int* h2 = (const unsigned int*)h;

    for (int i = 0; i < 16; ++i) {
        int node = row0 + wid * 16 + i;
        unsigned int o = 0u;
        if (node < nrows) {
            int beg = rowptr[node], end = rowptr[node + 1];
            float ax = 0.f, ay = 0.f;
            int e = beg;
            for (; e + 4 <= end; e += 4) {          // 4-deep unroll: 4 outstanding gathers
                int s0 = csr[e], s1 = csr[e + 1], s2 = csr[e + 2], s3 = csr[e + 3];
                unsigned int v0 = h2[(size_t)s0 * 64 + lane];
                unsigned int v1 = h2[(size_t)s1 * 64 + lane];
                unsigned int v2 = h2[(size_t)s2 * 64 + lane];
                unsigned int v3 = h2[(size_t)s3 * 64 + lane];
                ax += lo16(v0) + lo16(v1) + lo16(v2) + lo16(v3);
                ay += hi16(v0) + hi16(v1) + hi16(v2) + hi16(v3);
            }
            for (; e < end; ++e) {
                unsigned int v = h2[(size_t)csr[e] * 64 + lane];
                ax += lo16(v); ay += hi16(v);
            }
            unsigned int hv = h2[(size_t)node * 64 + lane];
            ax += ep * lo16(hv); ay += ep * hi16(hv);
            o = pack16(ax, ay);
        }
        *(unsigned int*)&As[wid * 16 + i][lane * 2] = o;
    }
    __syncthreads();
    gemm_core(As, Wt, Z, stats, stats + 128, nrows, row0, tid);
}

// ---------------- gemmB: fused BN1+ReLU staging + GEMM2 + stats ----------------

__global__ __launch_bounds__(256) void gemmB_kernel(
    const unsigned short* __restrict__ Zin, const float* __restrict__ statsIn,
    const float* __restrict__ g, const float* __restrict__ beta,
    const unsigned short* __restrict__ Wt, unsigned short* __restrict__ Zout,
    float* __restrict__ statsOut, int nrows)
{
    __shared__ __attribute__((aligned(16))) unsigned short As[GEMM_BM][LDSP];
    __shared__ float abn[DIM], shbn[DIM];
    int tid = threadIdx.x;
    int row0 = blockIdx.x * GEMM_BM;

    if (tid < DIM) {
        const float invN = 1.0f / (float)N_NODES;
        float m = statsIn[tid] * invN;
        float var = statsIn[128 + tid] * invN - m * m;
        float s = g[tid] * rsqrtf(var + BN_EPS);
        abn[tid] = s;
        shbn[tid] = beta[tid] - s * m;
    }
    __syncthreads();

#pragma unroll
    for (int it = 0; it < 4; ++it) {
        int c = tid + it * 256;
        int r = c >> 4, kc = c & 15;
        bf16x8 o = {0, 0, 0, 0, 0, 0, 0, 0};
        if (row0 + r < nrows) {     // pad rows stay exact 0 (keeps GEMM2 stats exact)
            bf16x8 v = *(const bf16x8*)(Zin + (size_t)(row0 + r) * DIM + kc * 8);
#pragma unroll
            for (int cc = 0; cc < 8; ++cc) {
                int col = kc * 8 + cc;
                float f = bf2f((unsigned short)v[cc]);
                f = fmaxf(fmaf(abn[col], f, shbn[col]), 0.f);
                o[cc] = (short)f2bf(f);
            }
        }
        *(bf16x8*)&As[r][kc * 8] = o;
    }
    __syncthreads();
    gemm_core(As, Wt, Zout, statsOut, statsOut + 128, nrows, row0, tid);
}

// ---------------- bnpool: BN2+ReLU apply + h write + fused graph sum-pool ----------------
// Rows sorted by graph_id: register segment-sums, flush atomics on boundary (~2/block).

__global__ __launch_bounds__(256) void bnpool_kernel(
    const unsigned short* __restrict__ Zin, const float* __restrict__ stats,
    const float* __restrict__ g, const float* __restrict__ beta,
    const int* __restrict__ gid, unsigned short* __restrict__ hout,
    float* __restrict__ pooled, int nrows)
{
    __shared__ float abn[DIM], shbn[DIM];
    int tid = threadIdx.x;
    if (tid < DIM) {
        const float invN = 1.0f / (float)N_NODES;
        float m = stats[tid] * invN;
        float var = stats[128 + tid] * invN - m * m;
        float s = g[tid] * rsqrtf(var + BN_EPS);
        abn[tid] = s;
        shbn[tid] = beta[tid] - s * m;
    }
    __syncthreads();

    int row0 = blockIdx.x * GEMM_BM;
    int lane = tid & 63, w = tid >> 6;
    int c0 = lane * 2;
    float a0 = abn[c0], a1 = abn[c0 + 1], s0 = shbn[c0], s1 = shbn[c0 + 1];
    const unsigned int* Z2 = (const unsigned int*)Zin;
    unsigned int* H2 = (unsigned int*)hout;

    float px = 0.f, py = 0.f;
    int gcur = -1;
    for (int i = 0; i < 16; ++i) {
        int r = row0 + w * 16 + i;
        if (r >= nrows) break;
        int gg = gid[r];
        if (gg != gcur) {
            if (gcur >= 0) {
                atomicAdd(&pooled[(size_t)gcur * DIM + c0], px);
                atomicAdd(&pooled[(size_t)gcur * DIM + c0 + 1], py);
            }
            gcur = gg; px = 0.f; py = 0.f;
        }
        unsigned int v = Z2[(size_t)r * 64 + lane];
        float f0 = fmaxf(fmaf(a0, lo16(v), s0), 0.f);
        float f1 = fmaxf(fmaf(a1, hi16(v), s1), 0.f);
        unsigned int o = pack16(f0, f1);
        H2[(size_t)r * 64 + lane] = o;
        px += lo16(o);   // pool the bf16-rounded h (matches reference h path numerics)
        py += hi16(o);
    }
    if (gcur >= 0) {
        atomicAdd(&pooled[(size_t)gcur * DIM + c0], px);
        atomicAdd(&pooled[(size_t)gcur * DIM + c0 + 1], py);
    }
}

// ---------------- graph sum-pool for layer 0 (exact fp32 x) ----------------

__global__ __launch_bounds__(256) void pool_kernel(
    const float* __restrict__ h, const int* __restrict__ gptr, float* __restrict__ outp)
{
    __shared__ float red[DIM];
    int g = blockIdx.x;
    int c = threadIdx.x & 127;
    int half = threadIdx.x >> 7;
    int beg = gptr[g], end = gptr[g + 1];
    float acc = 0.f;
    for (int n = beg + half; n < end; n += 2) acc += h[(size_t)n * DIM + c];
    if (half == 1) red[c] = acc;
    __syncthreads();
    if (half == 0) outp[(size_t)g * DIM + c] = acc + red[c];
}

// ---------------- final readout ----------------

__global__ __launch_bounds__(256) void final_kernel(
    const float* __restrict__ pooledH, const float* __restrict__ Wp,
    const float* __restrict__ bp, float* __restrict__ outp)
{
    int t = blockIdx.x * blockDim.x + threadIdx.x;
    if (t >= N_GRAPHS * N_CLASSES) return;
    int g = t >> 4, c = t & 15;
    float acc = 0.f;
    for (int l = 0; l < N_LAYERS; ++l) {
        const float* ph = pooledH + ((size_t)l * N_GRAPHS + g) * DIM;
        const float* w = Wp + (size_t)l * DIM * N_CLASSES + c;
        float a = 0.f;
        for (int k = 0; k < DIM; ++k) a = fmaf(ph[k], w[k * N_CLASSES], a);
        acc += a + bp[l * N_CLASSES + c];
    }
    outp[t] = acc;
}

// ---------------- host launcher ----------------

extern "C" void kernel_launch(void* const* d_in, const int* in_sizes, int n_in,
                              void* d_out, int out_size, void* d_ws, size_t ws_size,
                              hipStream_t stream) {
    const float* x     = (const float*)d_in[0];
    const float* eps   = (const float*)d_in[1];
    const float* W1    = (const float*)d_in[2];
    const float* g1    = (const float*)d_in[4];
    const float* beta1 = (const float*)d_in[5];
    const float* W2    = (const float*)d_in[6];
    const float* g2    = (const float*)d_in[8];
    const float* beta2 = (const float*)d_in[9];
    const float* Wp    = (const float*)d_in[10];
    const float* bp    = (const float*)d_in[11];
    const int*   esrc  = (const int*)d_in[12];
    const int*   edst  = (const int*)d_in[13];
    const int*   gid   = (const int*)d_in[14];
    float* outp = (float*)d_out;

    char* ws = (char*)d_ws;
    size_t off = 0;
    auto alloc = [&](size_t bytes) {
        char* p = ws + off;
        off = (off + bytes + 255) & ~(size_t)255;
        return p;
    };
    unsigned short* xb  = (unsigned short*)alloc((size_t)N_NODES * DIM * 2);
    unsigned short* B0  = (unsigned short*)alloc((size_t)N_NODES * DIM * 2);  // h ping
    unsigned short* B1  = (unsigned short*)alloc((size_t)N_NODES * DIM * 2);  // h pong
    unsigned short* ZB  = (unsigned short*)alloc((size_t)N_NODES * DIM * 2);  // Z1
    unsigned short* Z2B = (unsigned short*)alloc((size_t)N_NODES * DIM * 2);  // Z2
    unsigned short* Wt1 = (unsigned short*)alloc((size_t)(N_LAYERS - 1) * DIM * DIM * 2);
    unsigned short* Wt2 = (unsigned short*)alloc((size_t)(N_LAYERS - 1) * DIM * DIM * 2);
    int*   csr     = (int*)alloc((size_t)N_EDGES * 4);
    int*   deg     = (int*)alloc((N_NODES + 1) * 4);
    int*   rowptr  = (int*)alloc((N_NODES + 1) * 4);
    int*   cursor  = (int*)alloc((N_NODES + 1) * 4);
    int*   part    = (int*)alloc(64 * 4);
    int*   gcnt    = (int*)alloc(300 * 4);
    int*   growptr = (int*)alloc(300 * 4);
    float* stats   = (float*)alloc(8 * 256 * 4);   // [2*(L-1)] x {colsum[128], colsumsq[128]}
    float* pooledH = (float*)alloc((size_t)N_LAYERS * N_GRAPHS * DIM * 4);

    hipMemsetAsync(deg, 0, N_NODES * 4, stream);
    hipMemsetAsync(gcnt, 0, 256 * 4, stream);
    hipMemsetAsync(stats, 0, 8 * 256 * 4, stream);
    hipMemsetAsync(pooledH, 0, (size_t)N_LAYERS * N_GRAPHS * DIM * 4, stream);

    const int nsb = (N_NODES + 1023) / 1024;   // 49 scan blocks
    deg_kernel<<<(N_EDGES + 255) / 256, 256, 0, stream>>>(edst, deg, N_EDGES);
    scan_part_kernel<<<nsb, 1024, 0, stream>>>(deg, part, N_NODES);
    scan_mid_kernel<<<1, 64, 0, stream>>>(part, nsb, rowptr, N_NODES);
    scan_final_kernel<<<nsb, 1024, 0, stream>>>(deg, part, rowptr, cursor, N_NODES);
    fill_csr_kernel<<<(N_EDGES + 255) / 256, 256, 0, stream>>>(esrc, edst, cursor, csr, N_EDGES);
    gcount_kernel<<<(N_NODES + 255) / 256, 256, 0, stream>>>(gid, gcnt, N_NODES);
    scan_small_kernel<<<1, 1024, 0, stream>>>(gcnt, growptr, N_GRAPHS);

    f2b_kernel<<<(N_NODES * DIM / 4 + 255) / 256, 256, 0, stream>>>(x, xb, N_NODES * DIM / 4);
    wconv_kernel<<<((N_LAYERS - 1) * DIM * DIM + 255) / 256, 256, 0, stream>>>(W1, Wt1, N_LAYERS - 1);
    wconv_kernel<<<((N_LAYERS - 1) * DIM * DIM + 255) / 256, 256, 0, stream>>>(W2, Wt2, N_LAYERS - 1);

    pool_kernel<<<N_GRAPHS, 256, 0, stream>>>(x, growptr, pooledH);   // layer 0 exact

    const int ngrid = (N_NODES + GEMM_BM - 1) / GEMM_BM;   // 782
    unsigned short* hb = xb;
    unsigned short* nb = B0;
    for (int l = 0; l < N_LAYERS - 1; ++l) {
        gemmA_kernel<<<ngrid, 256, 0, stream>>>(
            hb, rowptr, csr, eps, l, Wt1 + (size_t)l * DIM * DIM, ZB,
            stats + (size_t)(2 * l) * 256, N_NODES);
        gemmB_kernel<<<ngrid, 256, 0, stream>>>(
            ZB, stats + (size_t)(2 * l) * 256, g1 + l * DIM, beta1 + l * DIM,
            Wt2 + (size_t)l * DIM * DIM, Z2B, stats + (size_t)(2 * l + 1) * 256, N_NODES);
        bnpool_kernel<<<ngrid, 256, 0, stream>>>(
            Z2B, stats + (size_t)(2 * l + 1) * 256, g2 + l * DIM, beta2 + l * DIM,
            gid, nb, pooledH + (size_t)(l + 1) * N_GRAPHS * DIM, N_NODES);

        hb = nb;
        nb = (hb == B0) ? B1 : B0;
    }

    final_kernel<<<(N_GRAPHS * N_CLASSES + 255) / 256, 256, 0, stream>>>(pooledH, Wp, bp, outp);
}

// Round 5
// 734.028 us; speedup vs baseline: 2.2831x; 1.1849x over previous
//
#include <hip/hip_runtime.h>

#define N_NODES  50000
#define N_EDGES  800000
#define DIM      128
#define N_GRAPHS 256
#define N_CLASSES 16
#define N_LAYERS 5
#define BN_EPS   1e-5f

#define GEMM_BM 64
#define LDSP 136   // padded LDS row stride (bf16 elems): 272B breaks power-of-2 banking

typedef short bf16x8 __attribute__((ext_vector_type(8)));
typedef float f32x4  __attribute__((ext_vector_type(4)));

__device__ __forceinline__ float bf2f(unsigned short u) {
    unsigned int x = ((unsigned int)u) << 16;
    return __builtin_bit_cast(float, x);
}
__device__ __forceinline__ unsigned short f2bf(float f) {
    unsigned int x = __builtin_bit_cast(unsigned int, f);
    x += 0x7fffu + ((x >> 16) & 1u);   // RNE
    return (unsigned short)(x >> 16);
}
__device__ __forceinline__ float lo16(unsigned int v) { return bf2f((unsigned short)(v & 0xffffu)); }
__device__ __forceinline__ float hi16(unsigned int v) { return bf2f((unsigned short)(v >> 16)); }
__device__ __forceinline__ unsigned int pack16(float a, float b) {
    return (unsigned int)f2bf(a) | ((unsigned int)f2bf(b) << 16);
}

// ---------------- CSR / histogram build ----------------

__global__ void deg_kernel(const int* __restrict__ dst, int* __restrict__ deg, int e_count) {
    int e = blockIdx.x * blockDim.x + threadIdx.x;
    if (e < e_count) atomicAdd(&deg[dst[e]], 1);
}

__global__ void fill_csr_kernel(const int* __restrict__ src, const int* __restrict__ dst,
                                int* __restrict__ cursor, int* __restrict__ csr, int e_count) {
    int e = blockIdx.x * blockDim.x + threadIdx.x;
    if (e < e_count) {
        int d = dst[e];
        int p = atomicAdd(&cursor[d], 1);
        csr[p] = src[e];
    }
}

__global__ void gcount_kernel(const int* __restrict__ gid, int* __restrict__ cnt, int n) {
    int i = blockIdx.x * blockDim.x + threadIdx.x;
    if (i < n) atomicAdd(&cnt[gid[i]], 1);
}

// ---------------- fast 3-phase exclusive scan ----------------

__global__ __launch_bounds__(1024) void scan_part_kernel(const int* __restrict__ in,
                                                         int* __restrict__ part, int n) {
    __shared__ int red[16];
    int tid = threadIdx.x;
    int i = blockIdx.x * 1024 + tid;
    int v = (i < n) ? in[i] : 0;
#pragma unroll
    for (int d = 1; d < 64; d <<= 1) v += __shfl_xor(v, d, 64);
    int lane = tid & 63, w = tid >> 6;
    if (lane == 0) red[w] = v;
    __syncthreads();
    if (tid == 0) {
        int s = 0;
#pragma unroll
        for (int k = 0; k < 16; ++k) s += red[k];
        part[blockIdx.x] = s;
    }
}

__global__ void scan_mid_kernel(int* __restrict__ part, int nb,
                                int* __restrict__ total_out, int total_idx) {
    int lane = threadIdx.x;
    int orig = (lane < nb) ? part[lane] : 0;
    int v = orig;
#pragma unroll
    for (int d = 1; d < 64; d <<= 1) {
        int t = __shfl_up(v, d, 64);
        if (lane >= d) v += t;
    }
    if (lane < nb) part[lane] = v - orig;
    if (lane == 63) total_out[total_idx] = v;
}

__global__ __launch_bounds__(1024) void scan_final_kernel(const int* __restrict__ in,
                                                          const int* __restrict__ part,
                                                          int* __restrict__ rowptr,
                                                          int* __restrict__ cursor, int n) {
    __shared__ int woff[16];
    int tid = threadIdx.x;
    int i = blockIdx.x * 1024 + tid;
    int v = (i < n) ? in[i] : 0;
    int lane = tid & 63, w = tid >> 6;
    int x = v;
#pragma unroll
    for (int d = 1; d < 64; d <<= 1) {
        int t = __shfl_up(x, d, 64);
        if (lane >= d) x += t;
    }
    if (lane == 63) woff[w] = x;
    __syncthreads();
    if (tid == 0) {
        int s = 0;
#pragma unroll
        for (int k = 0; k < 16; ++k) { int t = woff[k]; woff[k] = s; s += t; }
    }
    __syncthreads();
    int excl = part[blockIdx.x] + woff[w] + x - v;
    if (i < n) { rowptr[i] = excl; cursor[i] = excl; }
}

__global__ __launch_bounds__(1024) void scan_small_kernel(const int* __restrict__ in,
                                                          int* __restrict__ outp, int n) {
    __shared__ int wsum[16], woff[16];
    int tid = threadIdx.x;
    int v = (tid < n) ? in[tid] : 0;
    int lane = tid & 63, w = tid >> 6;
    int x = v;
#pragma unroll
    for (int d = 1; d < 64; d <<= 1) {
        int t = __shfl_up(x, d, 64);
        if (lane >= d) x += t;
    }
    if (lane == 63) wsum[w] = x;
    __syncthreads();
    if (tid == 0) {
        int s = 0;
#pragma unroll
        for (int k = 0; k < 16; ++k) { woff[k] = s; s += wsum[k]; }
        wsum[15] = s;
    }
    __syncthreads();
    if (tid < n) outp[tid] = woff[w] + x - v;
    if (tid == 0) outp[n] = wsum[15];
}

// ---------------- conversions ----------------

__global__ void f2b_kernel(const float* __restrict__ in, unsigned short* __restrict__ outp, int n4) {
    int i = blockIdx.x * blockDim.x + threadIdx.x;
    if (i >= n4) return;
    float4 v = ((const float4*)in)[i];
    unsigned int a = pack16(v.x, v.y);
    unsigned int b = pack16(v.z, v.w);
    ((uint2*)outp)[i] = make_uint2(a, b);
}

__global__ void wconv_kernel(const float* __restrict__ W, unsigned short* __restrict__ Wt, int nmat) {
    int t = blockIdx.x * blockDim.x + threadIdx.x;
    if (t >= nmat * DIM * DIM) return;
    int m = t >> 14;
    int rem = t & 16383;
    int k = rem >> 7;
    int c = rem & 127;
    Wt[((size_t)m << 14) + (size_t)c * DIM + k] = f2bf(W[t]);
}

// ---------------- 8-wave GEMM core: 64x128 LDS A-tile, B-frags from L2 ----------------
// Wave wid: m-quarter mq=wid&3 (rows mq*16..+15), col-half ch=wid>>2 (cols ch*64..+63).
// mfma_f32_16x16x32_bf16 layouts verified in rounds 3/4 (asymmetric weights passed).

__device__ __forceinline__ void gemm_core8(
    unsigned short (*As)[LDSP], const unsigned short* __restrict__ Wt,
    unsigned short* __restrict__ Z, float* __restrict__ colsum, float* __restrict__ colsumsq,
    int nrows, int row0, int tid)
{
    int wid = tid >> 6, lane = tid & 63;
    int mq = wid & 3, ch = wid >> 2;
    int m0 = mq * 16;
    int lrow = lane & 15;
    int lk = (lane >> 4) * 8;

    f32x4 acc[4];
#pragma unroll
    for (int n = 0; n < 4; ++n) acc[n] = (f32x4){0.f, 0.f, 0.f, 0.f};

#pragma unroll
    for (int kk = 0; kk < 4; ++kk) {
        int k0 = kk * 32;
        bf16x8 a = *(const bf16x8*)&As[m0 + lrow][k0 + lk];
#pragma unroll
        for (int n = 0; n < 4; ++n) {
            bf16x8 b = *(const bf16x8*)(Wt + (size_t)(ch * 64 + n * 16 + lrow) * DIM + k0 + lk);
            acc[n] = __builtin_amdgcn_mfma_f32_16x16x32_bf16(a, b, acc[n], 0, 0, 0);
        }
    }

    // epilogue: bf16 Z store + fp32 column stats (pad rows contribute exact 0)
    int r0 = row0 + m0 + (lane >> 4) * 4;
    float sarr[4], qarr[4];
#pragma unroll
    for (int n = 0; n < 4; ++n) {
        int col = ch * 64 + n * 16 + lrow;
        float s = 0.f, q = 0.f;
#pragma unroll
        for (int j = 0; j < 4; ++j) {
            float v = acc[n][j];
            int row = r0 + j;
            if (row < nrows) Z[(size_t)row * DIM + col] = f2bf(v);
            s += v; q += v * v;
        }
        s += __shfl_xor(s, 16); q += __shfl_xor(q, 16);
        s += __shfl_xor(s, 32); q += __shfl_xor(q, 32);
        sarr[n] = s; qarr[n] = q;
    }

    __syncthreads();                   // done with As; reuse as fp32 scratch (8KB of 17.4KB)
    float* red = (float*)&As[0][0];    // [8 waves][256]: sum at +col, sumsq at +128+col
    if (lane < 16) {
#pragma unroll
        for (int n = 0; n < 4; ++n) {
            int col = ch * 64 + n * 16 + lrow;
            red[wid * 256 + col]       = sarr[n];
            red[wid * 256 + 128 + col] = qarr[n];
        }
    }
    __syncthreads();
    if (tid < 128) {
        int col = tid;
        int base = (col >> 6) * 4 * 256;   // waves {0..3} own cols 0-63, {4..7} own 64-127
        float ts = red[base + col] + red[base + 256 + col]
                 + red[base + 512 + col] + red[base + 768 + col];
        float tq = red[base + 128 + col] + red[base + 384 + col]
                 + red[base + 640 + col] + red[base + 896 + col];
        atomicAdd(&colsum[col], ts);
        atomicAdd(&colsumsq[col], tq);
    }
}

// ---------------- gemmA: wave-cooperative SpMM gather + GEMM1 + stats ----------------
// sub = lane>>4 picks 1 of 4 edges, chunk = lane&15 picks 16B of the 256B row:
// one dwordx4 instruction gathers 4 whole rows; x2 unroll = 8 rows in flight.

__global__ __launch_bounds__(512) void gemmA_kernel(
    const unsigned short* __restrict__ h, const int* __restrict__ rowptr,
    const int* __restrict__ csr, const float* __restrict__ epsArr, int l,
    const unsigned short* __restrict__ Wt, unsigned short* __restrict__ Z,
    float* __restrict__ stats, int nrows)
{
    __shared__ __attribute__((aligned(16))) unsigned short As[GEMM_BM][LDSP];
    int tid = threadIdx.x;
    int row0 = blockIdx.x * GEMM_BM;
    int wid = tid >> 6, lane = tid & 63;
    int sub = lane >> 4, chunk = lane & 15;
    float ep = 1.0f + epsArr[l];

    for (int i = 0; i < 8; ++i) {
        int node = row0 + wid * 8 + i;
        float a8[8];
#pragma unroll
        for (int j = 0; j < 8; ++j) a8[j] = 0.f;
        if (node < nrows) {
            int beg = rowptr[node], end = rowptr[node + 1];
            int e = beg;
            for (; e + 8 <= end; e += 8) {
                int s0 = csr[e + sub];
                int s1 = csr[e + 4 + sub];
                bf16x8 v0 = *(const bf16x8*)(h + (size_t)s0 * DIM + chunk * 8);
                bf16x8 v1 = *(const bf16x8*)(h + (size_t)s1 * DIM + chunk * 8);
#pragma unroll
                for (int j = 0; j < 8; ++j)
                    a8[j] += bf2f((unsigned short)v0[j]) + bf2f((unsigned short)v1[j]);
            }
            for (; e + 4 <= end; e += 4) {
                int s0 = csr[e + sub];
                bf16x8 v0 = *(const bf16x8*)(h + (size_t)s0 * DIM + chunk * 8);
#pragma unroll
                for (int j = 0; j < 8; ++j) a8[j] += bf2f((unsigned short)v0[j]);
            }
            int rmn = end - e;
            if (sub < rmn) {
                int s0 = csr[e + sub];
                bf16x8 v0 = *(const bf16x8*)(h + (size_t)s0 * DIM + chunk * 8);
#pragma unroll
                for (int j = 0; j < 8; ++j) a8[j] += bf2f((unsigned short)v0[j]);
            }
            // combine the 4 sub-group partials (all lanes end with the total)
#pragma unroll
            for (int j = 0; j < 8; ++j) {
                a8[j] += __shfl_xor(a8[j], 16);
                a8[j] += __shfl_xor(a8[j], 32);
            }
            // self term
            bf16x8 hv = *(const bf16x8*)(h + (size_t)node * DIM + chunk * 8);
#pragma unroll
            for (int j = 0; j < 8; ++j) a8[j] += ep * bf2f((unsigned short)hv[j]);
        }
        if (sub == 0) {
            bf16x8 o;
#pragma unroll
            for (int j = 0; j < 8; ++j) o[j] = (short)f2bf(a8[j]);
            *(bf16x8*)&As[wid * 8 + i][chunk * 8] = o;
        }
    }
    __syncthreads();
    gemm_core8(As, Wt, Z, stats, stats + 128, nrows, row0, tid);
}

// ---------------- gemmB: fused BN1+ReLU staging + GEMM2 + stats ----------------

__global__ __launch_bounds__(512) void gemmB_kernel(
    const unsigned short* __restrict__ Zin, const float* __restrict__ statsIn,
    const float* __restrict__ g, const float* __restrict__ beta,
    const unsigned short* __restrict__ Wt, unsigned short* __restrict__ Zout,
    float* __restrict__ statsOut, int nrows)
{
    __shared__ __attribute__((aligned(16))) unsigned short As[GEMM_BM][LDSP];
    __shared__ float abn[DIM], shbn[DIM];
    int tid = threadIdx.x;
    int row0 = blockIdx.x * GEMM_BM;

    if (tid < DIM) {
        const float invN = 1.0f / (float)N_NODES;
        float m = statsIn[tid] * invN;
        float var = statsIn[128 + tid] * invN - m * m;
        float s = g[tid] * rsqrtf(var + BN_EPS);
        abn[tid] = s;
        shbn[tid] = beta[tid] - s * m;
    }
    __syncthreads();

#pragma unroll
    for (int it = 0; it < 2; ++it) {
        int c = tid + it * 512;
        int r = c >> 4, kc = c & 15;
        bf16x8 o = {0, 0, 0, 0, 0, 0, 0, 0};
        if (row0 + r < nrows) {     // pad rows stay exact 0
            bf16x8 v = *(const bf16x8*)(Zin + (size_t)(row0 + r) * DIM + kc * 8);
#pragma unroll
            for (int cc = 0; cc < 8; ++cc) {
                int col = kc * 8 + cc;
                float f = bf2f((unsigned short)v[cc]);
                f = fmaxf(fmaf(abn[col], f, shbn[col]), 0.f);
                o[cc] = (short)f2bf(f);
            }
        }
        *(bf16x8*)&As[r][kc * 8] = o;
    }
    __syncthreads();
    gemm_core8(As, Wt, Zout, statsOut, statsOut + 128, nrows, row0, tid);
}

// ---------------- bnpool: BN2+ReLU apply + h write + fused graph sum-pool ----------------

__global__ __launch_bounds__(256) void bnpool_kernel(
    const unsigned short* __restrict__ Zin, const float* __restrict__ stats,
    const float* __restrict__ g, const float* __restrict__ beta,
    const int* __restrict__ gid, unsigned short* __restrict__ hout,
    float* __restrict__ pooled, int nrows)
{
    __shared__ float abn[DIM], shbn[DIM];
    int tid = threadIdx.x;
    if (tid < DIM) {
        const float invN = 1.0f / (float)N_NODES;
        float m = stats[tid] * invN;
        float var = stats[128 + tid] * invN - m * m;
        float s = g[tid] * rsqrtf(var + BN_EPS);
        abn[tid] = s;
        shbn[tid] = beta[tid] - s * m;
    }
    __syncthreads();

    int row0 = blockIdx.x * GEMM_BM;
    int lane = tid & 63, w = tid >> 6;
    int c0 = lane * 2;
    float a0 = abn[c0], a1 = abn[c0 + 1], s0 = shbn[c0], s1 = shbn[c0 + 1];
    const unsigned int* Z2 = (const unsigned int*)Zin;
    unsigned int* H2 = (unsigned int*)hout;

    float px = 0.f, py = 0.f;
    int gcur = -1;
    for (int i = 0; i < 16; ++i) {
        int r = row0 + w * 16 + i;
        if (r >= nrows) break;
        int gg = gid[r];
        if (gg != gcur) {
            if (gcur >= 0) {
                atomicAdd(&pooled[(size_t)gcur * DIM + c0], px);
                atomicAdd(&pooled[(size_t)gcur * DIM + c0 + 1], py);
            }
            gcur = gg; px = 0.f; py = 0.f;
        }
        unsigned int v = Z2[(size_t)r * 64 + lane];
        float f0 = fmaxf(fmaf(a0, lo16(v), s0), 0.f);
        float f1 = fmaxf(fmaf(a1, hi16(v), s1), 0.f);
        unsigned int o = pack16(f0, f1);
        H2[(size_t)r * 64 + lane] = o;
        px += lo16(o);
        py += hi16(o);
    }
    if (gcur >= 0) {
        atomicAdd(&pooled[(size_t)gcur * DIM + c0], px);
        atomicAdd(&pooled[(size_t)gcur * DIM + c0 + 1], py);
    }
}

// ---------------- graph sum-pool for layer 0 (exact fp32 x) ----------------

__global__ __launch_bounds__(256) void pool_kernel(
    const float* __restrict__ h, const int* __restrict__ gptr, float* __restrict__ outp)
{
    __shared__ float red[DIM];
    int g = blockIdx.x;
    int c = threadIdx.x & 127;
    int half = threadIdx.x >> 7;
    int beg = gptr[g], end = gptr[g + 1];
    float acc = 0.f;
    for (int n = beg + half; n < end; n += 2) acc += h[(size_t)n * DIM + c];
    if (half == 1) red[c] = acc;
    __syncthreads();
    if (half == 0) outp[(size_t)g * DIM + c] = acc + red[c];
}

// ---------------- final readout ----------------

__global__ __launch_bounds__(256) void final_kernel(
    const float* __restrict__ pooledH, const float* __restrict__ Wp,
    const float* __restrict__ bp, float* __restrict__ outp)
{
    int t = blockIdx.x * blockDim.x + threadIdx.x;
    if (t >= N_GRAPHS * N_CLASSES) return;
    int g = t >> 4, c = t & 15;
    float acc = 0.f;
    for (int l = 0; l < N_LAYERS; ++l) {
        const float* ph = pooledH + ((size_t)l * N_GRAPHS + g) * DIM;
        const float* w = Wp + (size_t)l * DIM * N_CLASSES + c;
        float a = 0.f;
        for (int k = 0; k < DIM; ++k) a = fmaf(ph[k], w[k * N_CLASSES], a);
        acc += a + bp[l * N_CLASSES + c];
    }
    outp[t] = acc;
}

// ---------------- host launcher ----------------

extern "C" void kernel_launch(void* const* d_in, const int* in_sizes, int n_in,
                              void* d_out, int out_size, void* d_ws, size_t ws_size,
                              hipStream_t stream) {
    const float* x     = (const float*)d_in[0];
    const float* eps   = (const float*)d_in[1];
    const float* W1    = (const float*)d_in[2];
    const float* g1    = (const float*)d_in[4];
    const float* beta1 = (const float*)d_in[5];
    const float* W2    = (const float*)d_in[6];
    const float* g2    = (const float*)d_in[8];
    const float* beta2 = (const float*)d_in[9];
    const float* Wp    = (const float*)d_in[10];
    const float* bp    = (const float*)d_in[11];
    const int*   esrc  = (const int*)d_in[12];
    const int*   edst  = (const int*)d_in[13];
    const int*   gid   = (const int*)d_in[14];
    float* outp = (float*)d_out;

    char* ws = (char*)d_ws;
    size_t off = 0;
    auto alloc = [&](size_t bytes) {
        char* p = ws + off;
        off = (off + bytes + 255) & ~(size_t)255;
        return p;
    };
    unsigned short* xb  = (unsigned short*)alloc((size_t)N_NODES * DIM * 2);
    unsigned short* B0  = (unsigned short*)alloc((size_t)N_NODES * DIM * 2);  // h ping
    unsigned short* B1  = (unsigned short*)alloc((size_t)N_NODES * DIM * 2);  // h pong
    unsigned short* ZB  = (unsigned short*)alloc((size_t)N_NODES * DIM * 2);  // Z1
    unsigned short* Z2B = (unsigned short*)alloc((size_t)N_NODES * DIM * 2);  // Z2
    unsigned short* Wt1 = (unsigned short*)alloc((size_t)(N_LAYERS - 1) * DIM * DIM * 2);
    unsigned short* Wt2 = (unsigned short*)alloc((size_t)(N_LAYERS - 1) * DIM * DIM * 2);
    int*   csr     = (int*)alloc((size_t)N_EDGES * 4);
    int*   deg     = (int*)alloc((N_NODES + 1) * 4);
    int*   rowptr  = (int*)alloc((N_NODES + 1) * 4);
    int*   cursor  = (int*)alloc((N_NODES + 1) * 4);
    int*   part    = (int*)alloc(64 * 4);
    int*   gcnt    = (int*)alloc(300 * 4);
    int*   growptr = (int*)alloc(300 * 4);
    float* stats   = (float*)alloc(8 * 256 * 4);   // [2*(L-1)] x {colsum[128], colsumsq[128]}
    float* pooledH = (float*)alloc((size_t)N_LAYERS * N_GRAPHS * DIM * 4);

    hipMemsetAsync(deg, 0, N_NODES * 4, stream);
    hipMemsetAsync(gcnt, 0, 256 * 4, stream);
    hipMemsetAsync(stats, 0, 8 * 256 * 4, stream);
    hipMemsetAsync(pooledH, 0, (size_t)N_LAYERS * N_GRAPHS * DIM * 4, stream);

    const int nsb = (N_NODES + 1023) / 1024;   // 49 scan blocks
    deg_kernel<<<(N_EDGES + 255) / 256, 256, 0, stream>>>(edst, deg, N_EDGES);
    scan_part_kernel<<<nsb, 1024, 0, stream>>>(deg, part, N_NODES);
    scan_mid_kernel<<<1, 64, 0, stream>>>(part, nsb, rowptr, N_NODES);
    scan_final_kernel<<<nsb, 1024, 0, stream>>>(deg, part, rowptr, cursor, N_NODES);
    fill_csr_kernel<<<(N_EDGES + 255) / 256, 256, 0, stream>>>(esrc, edst, cursor, csr, N_EDGES);
    gcount_kernel<<<(N_NODES + 255) / 256, 256, 0, stream>>>(gid, gcnt, N_NODES);
    scan_small_kernel<<<1, 1024, 0, stream>>>(gcnt, growptr, N_GRAPHS);

    f2b_kernel<<<(N_NODES * DIM / 4 + 255) / 256, 256, 0, stream>>>(x, xb, N_NODES * DIM / 4);
    wconv_kernel<<<((N_LAYERS - 1) * DIM * DIM + 255) / 256, 256, 0, stream>>>(W1, Wt1, N_LAYERS - 1);
    wconv_kernel<<<((N_LAYERS - 1) * DIM * DIM + 255) / 256, 256, 0, stream>>>(W2, Wt2, N_LAYERS - 1);

    pool_kernel<<<N_GRAPHS, 256, 0, stream>>>(x, growptr, pooledH);   // layer 0 exact

    const int ngrid = (N_NODES + GEMM_BM - 1) / GEMM_BM;   // 782
    unsigned short* hb = xb;
    unsigned short* nb = B0;
    for (int l = 0; l < N_LAYERS - 1; ++l) {
        gemmA_kernel<<<ngrid, 512, 0, stream>>>(
            hb, rowptr, csr, eps, l, Wt1 + (size_t)l * DIM * DIM, ZB,
            stats + (size_t)(2 * l) * 256, N_NODES);
        gemmB_kernel<<<ngrid, 512, 0, stream>>>(
            ZB, stats + (size_t)(2 * l) * 256, g1 + l * DIM, beta1 + l * DIM,
            Wt2 + (size_t)l * DIM * DIM, Z2B, stats + (size_t)(2 * l + 1) * 256, N_NODES);
        bnpool_kernel<<<ngrid, 256, 0, stream>>>(
            Z2B, stats + (size_t)(2 * l + 1) * 256, g2 + l * DIM, beta2 + l * DIM,
            gid, nb, pooledH + (size_t)(l + 1) * N_GRAPHS * DIM, N_NODES);

        hb = nb;
        nb = (hb == B0) ? B1 : B0;
    }

    final_kernel<<<(N_GRAPHS * N_CLASSES + 255) / 256, 256, 0, stream>>>(pooledH, Wp, bp, outp);
}

// Round 6
// 666.792 us; speedup vs baseline: 2.5133x; 1.1008x over previous
//
#include <hip/hip_runtime.h>

#define N_NODES  50000
#define N_EDGES  800000
#define DIM      128
#define N_GRAPHS 256
#define N_CLASSES 16
#define N_LAYERS 5
#define BN_EPS   1e-5f

#define GEMM_BM 64
#define LDSP 136   // padded LDS row stride (bf16 elems): 272B breaks power-of-2 banking

typedef short bf16x8 __attribute__((ext_vector_type(8)));
typedef float f32x4  __attribute__((ext_vector_type(4)));

__device__ __forceinline__ float bf2f(unsigned short u) {
    unsigned int x = ((unsigned int)u) << 16;
    return __builtin_bit_cast(float, x);
}
__device__ __forceinline__ unsigned short f2bf(float f) {
    unsigned int x = __builtin_bit_cast(unsigned int, f);
    x += 0x7fffu + ((x >> 16) & 1u);   // RNE
    return (unsigned short)(x >> 16);
}
__device__ __forceinline__ float lo16(unsigned int v) { return bf2f((unsigned short)(v & 0xffffu)); }
__device__ __forceinline__ float hi16(unsigned int v) { return bf2f((unsigned short)(v >> 16)); }
__device__ __forceinline__ unsigned int pack16(float a, float b) {
    return (unsigned int)f2bf(a) | ((unsigned int)f2bf(b) << 16);
}

// ---------------- CSR / histogram build ----------------

__global__ void deg_kernel(const int* __restrict__ dst, int* __restrict__ deg, int e_count) {
    int e = blockIdx.x * blockDim.x + threadIdx.x;
    if (e < e_count) atomicAdd(&deg[dst[e]], 1);
}

__global__ void fill_csr_kernel(const int* __restrict__ src, const int* __restrict__ dst,
                                int* __restrict__ cursor, int* __restrict__ csr, int e_count) {
    int e = blockIdx.x * blockDim.x + threadIdx.x;
    if (e < e_count) {
        int d = dst[e];
        int p = atomicAdd(&cursor[d], 1);
        csr[p] = src[e];
    }
}

// graph_ids sorted -> per-graph ranges via boundary detection (no atomics).
__global__ void gbound_kernel(const int* __restrict__ gid, int* __restrict__ gptr, int n, int G) {
    int i = blockIdx.x * blockDim.x + threadIdx.x;
    if (i >= n) return;
    int cur = gid[i];
    int prev = (i == 0) ? -1 : gid[i - 1];
    for (int g = prev + 1; g <= cur; ++g) gptr[g] = i;
    if (i == n - 1) {
        for (int g = cur + 1; g <= G; ++g) gptr[g] = n;
    }
}

// ---------------- fast 3-phase exclusive scan (rowptr over 50000 degrees) ----------------

__global__ __launch_bounds__(1024) void scan_part_kernel(const int* __restrict__ in,
                                                         int* __restrict__ part, int n) {
    __shared__ int red[16];
    int tid = threadIdx.x;
    int i = blockIdx.x * 1024 + tid;
    int v = (i < n) ? in[i] : 0;
#pragma unroll
    for (int d = 1; d < 64; d <<= 1) v += __shfl_xor(v, d, 64);
    int lane = tid & 63, w = tid >> 6;
    if (lane == 0) red[w] = v;
    __syncthreads();
    if (tid == 0) {
        int s = 0;
#pragma unroll
        for (int k = 0; k < 16; ++k) s += red[k];
        part[blockIdx.x] = s;
    }
}

__global__ void scan_mid_kernel(int* __restrict__ part, int nb,
                                int* __restrict__ total_out, int total_idx) {
    int lane = threadIdx.x;
    int orig = (lane < nb) ? part[lane] : 0;
    int v = orig;
#pragma unroll
    for (int d = 1; d < 64; d <<= 1) {
        int t = __shfl_up(v, d, 64);
        if (lane >= d) v += t;
    }
    if (lane < nb) part[lane] = v - orig;
    if (lane == 63) total_out[total_idx] = v;
}

__global__ __launch_bounds__(1024) void scan_final_kernel(const int* __restrict__ in,
                                                          const int* __restrict__ part,
                                                          int* __restrict__ rowptr,
                                                          int* __restrict__ cursor, int n) {
    __shared__ int woff[16];
    int tid = threadIdx.x;
    int i = blockIdx.x * 1024 + tid;
    int v = (i < n) ? in[i] : 0;
    int lane = tid & 63, w = tid >> 6;
    int x = v;
#pragma unroll
    for (int d = 1; d < 64; d <<= 1) {
        int t = __shfl_up(x, d, 64);
        if (lane >= d) x += t;
    }
    if (lane == 63) woff[w] = x;
    __syncthreads();
    if (tid == 0) {
        int s = 0;
#pragma unroll
        for (int k = 0; k < 16; ++k) { int t = woff[k]; woff[k] = s; s += t; }
    }
    __syncthreads();
    int excl = part[blockIdx.x] + woff[w] + x - v;
    if (i < n) { rowptr[i] = excl; cursor[i] = excl; }
}

// ---------------- conversions ----------------

__global__ void f2b_kernel(const float* __restrict__ in, unsigned short* __restrict__ outp, int n4) {
    int i = blockIdx.x * blockDim.x + threadIdx.x;
    if (i >= n4) return;
    float4 v = ((const float4*)in)[i];
    unsigned int a = pack16(v.x, v.y);
    unsigned int b = pack16(v.z, v.w);
    ((uint2*)outp)[i] = make_uint2(a, b);
}

__global__ void wconv_kernel(const float* __restrict__ W, unsigned short* __restrict__ Wt, int nmat) {
    int t = blockIdx.x * blockDim.x + threadIdx.x;
    if (t >= nmat * DIM * DIM) return;
    int m = t >> 14;
    int rem = t & 16383;
    int k = rem >> 7;
    int c = rem & 127;
    Wt[((size_t)m << 14) + (size_t)c * DIM + k] = f2bf(W[t]);
}

// ---------------- 8-wave GEMM core: 64x128 LDS A-tile, B-frags from L2 ----------------
// Wave wid: m-quarter mq=wid&3 (rows mq*16..+15), col-half ch=wid>>2 (cols ch*64..+63).
// mfma_f32_16x16x32_bf16 layouts verified in rounds 3/4/5 (asymmetric weights passed).

__device__ __forceinline__ void gemm_core8(
    unsigned short (*As)[LDSP], const unsigned short* __restrict__ Wt,
    unsigned short* __restrict__ Z, float* __restrict__ colsum, float* __restrict__ colsumsq,
    int nrows, int row0, int tid)
{
    int wid = tid >> 6, lane = tid & 63;
    int mq = wid & 3, ch = wid >> 2;
    int m0 = mq * 16;
    int lrow = lane & 15;
    int lk = (lane >> 4) * 8;

    f32x4 acc[4];
#pragma unroll
    for (int n = 0; n < 4; ++n) acc[n] = (f32x4){0.f, 0.f, 0.f, 0.f};

#pragma unroll
    for (int kk = 0; kk < 4; ++kk) {
        int k0 = kk * 32;
        bf16x8 a = *(const bf16x8*)&As[m0 + lrow][k0 + lk];
#pragma unroll
        for (int n = 0; n < 4; ++n) {
            bf16x8 b = *(const bf16x8*)(Wt + (size_t)(ch * 64 + n * 16 + lrow) * DIM + k0 + lk);
            acc[n] = __builtin_amdgcn_mfma_f32_16x16x32_bf16(a, b, acc[n], 0, 0, 0);
        }
    }

    // epilogue: bf16 Z store + fp32 column stats (pad rows contribute exact 0)
    int r0 = row0 + m0 + (lane >> 4) * 4;
    float sarr[4], qarr[4];
#pragma unroll
    for (int n = 0; n < 4; ++n) {
        int col = ch * 64 + n * 16 + lrow;
        float s = 0.f, q = 0.f;
#pragma unroll
        for (int j = 0; j < 4; ++j) {
            float v = acc[n][j];
            int row = r0 + j;
            if (row < nrows) Z[(size_t)row * DIM + col] = f2bf(v);
            s += v; q += v * v;
        }
        s += __shfl_xor(s, 16); q += __shfl_xor(q, 16);
        s += __shfl_xor(s, 32); q += __shfl_xor(q, 32);
        sarr[n] = s; qarr[n] = q;
    }

    __syncthreads();                   // done with As; reuse as fp32 scratch
    float* red = (float*)&As[0][0];    // [8 waves][256]: sum at +col, sumsq at +128+col
    if (lane < 16) {
#pragma unroll
        for (int n = 0; n < 4; ++n) {
            int col = ch * 64 + n * 16 + lrow;
            red[wid * 256 + col]       = sarr[n];
            red[wid * 256 + 128 + col] = qarr[n];
        }
    }
    __syncthreads();
    if (tid < 128) {
        int col = tid;
        int base = (col >> 6) * 4 * 256;   // waves {0..3} own cols 0-63, {4..7} own 64-127
        float ts = red[base + col] + red[base + 256 + col]
                 + red[base + 512 + col] + red[base + 768 + col];
        float tq = red[base + 128 + col] + red[base + 384 + col]
                 + red[base + 640 + col] + red[base + 896 + col];
        atomicAdd(&colsum[col], ts);
        atomicAdd(&colsumsq[col], tq);
    }
}

// ---------------- gemmA: wave-cooperative SpMM gather + GEMM1 + stats ----------------
// sub = lane>>4 picks 1 of 4 edges, chunk = lane&15 picks 16B of the 256B row:
// one dwordx4 instruction gathers 4 whole rows; x4 unroll = 16 rows in flight.

__global__ __launch_bounds__(512) void gemmA_kernel(
    const unsigned short* __restrict__ h, const int* __restrict__ rowptr,
    const int* __restrict__ csr, const float* __restrict__ epsArr, int l,
    const unsigned short* __restrict__ Wt, unsigned short* __restrict__ Z,
    float* __restrict__ stats, int nrows)
{
    __shared__ __attribute__((aligned(16))) unsigned short As[GEMM_BM][LDSP];
    int tid = threadIdx.x;
    int row0 = blockIdx.x * GEMM_BM;
    int wid = tid >> 6, lane = tid & 63;
    int sub = lane >> 4, chunk = lane & 15;
    float ep = 1.0f + epsArr[l];

    for (int i = 0; i < 8; ++i) {
        int node = row0 + wid * 8 + i;
        float a8[8];
#pragma unroll
        for (int j = 0; j < 8; ++j) a8[j] = 0.f;
        if (node < nrows) {
            int beg = rowptr[node], end = rowptr[node + 1];
            int e = beg;
            for (; e + 16 <= end; e += 16) {       // 16 rows in flight (4 dwordx4/lane)
                int s0 = csr[e + sub];
                int s1 = csr[e + 4 + sub];
                int s2 = csr[e + 8 + sub];
                int s3 = csr[e + 12 + sub];
                bf16x8 v0 = *(const bf16x8*)(h + (size_t)s0 * DIM + chunk * 8);
                bf16x8 v1 = *(const bf16x8*)(h + (size_t)s1 * DIM + chunk * 8);
                bf16x8 v2 = *(const bf16x8*)(h + (size_t)s2 * DIM + chunk * 8);
                bf16x8 v3 = *(const bf16x8*)(h + (size_t)s3 * DIM + chunk * 8);
#pragma unroll
                for (int j = 0; j < 8; ++j)
                    a8[j] += (bf2f((unsigned short)v0[j]) + bf2f((unsigned short)v1[j]))
                           + (bf2f((unsigned short)v2[j]) + bf2f((unsigned short)v3[j]));
            }
            for (; e + 8 <= end; e += 8) {
                int s0 = csr[e + sub];
                int s1 = csr[e + 4 + sub];
                bf16x8 v0 = *(const bf16x8*)(h + (size_t)s0 * DIM + chunk * 8);
                bf16x8 v1 = *(const bf16x8*)(h + (size_t)s1 * DIM + chunk * 8);
#pragma unroll
                for (int j = 0; j < 8; ++j)
                    a8[j] += bf2f((unsigned short)v0[j]) + bf2f((unsigned short)v1[j]);
            }
            for (; e + 4 <= end; e += 4) {
                int s0 = csr[e + sub];
                bf16x8 v0 = *(const bf16x8*)(h + (size_t)s0 * DIM + chunk * 8);
#pragma unroll
                for (int j = 0; j < 8; ++j) a8[j] += bf2f((unsigned short)v0[j]);
            }
            int rmn = end - e;
            if (sub < rmn) {
                int s0 = csr[e + sub];
                bf16x8 v0 = *(const bf16x8*)(h + (size_t)s0 * DIM + chunk * 8);
#pragma unroll
                for (int j = 0; j < 8; ++j) a8[j] += bf2f((unsigned short)v0[j]);
            }
            // combine the 4 sub-group partials (all lanes end with the total)
#pragma unroll
            for (int j = 0; j < 8; ++j) {
                a8[j] += __shfl_xor(a8[j], 16);
                a8[j] += __shfl_xor(a8[j], 32);
            }
            // self term
            bf16x8 hv = *(const bf16x8*)(h + (size_t)node * DIM + chunk * 8);
#pragma unroll
            for (int j = 0; j < 8; ++j) a8[j] += ep * bf2f((unsigned short)hv[j]);
        }
        if (sub == 0) {
            bf16x8 o;
#pragma unroll
            for (int j = 0; j < 8; ++j) o[j] = (short)f2bf(a8[j]);
            *(bf16x8*)&As[wid * 8 + i][chunk * 8] = o;
        }
    }
    __syncthreads();
    gemm_core8(As, Wt, Z, stats, stats + 128, nrows, row0, tid);
}

// ---------------- gemmB: fused BN1+ReLU staging + GEMM2 + stats ----------------

__global__ __launch_bounds__(512) void gemmB_kernel(
    const unsigned short* __restrict__ Zin, const float* __restrict__ statsIn,
    const float* __restrict__ g, const float* __restrict__ beta,
    const unsigned short* __restrict__ Wt, unsigned short* __restrict__ Zout,
    float* __restrict__ statsOut, int nrows)
{
    __shared__ __attribute__((aligned(16))) unsigned short As[GEMM_BM][LDSP];
    __shared__ float abn[DIM], shbn[DIM];
    int tid = threadIdx.x;
    int row0 = blockIdx.x * GEMM_BM;

    if (tid < DIM) {
        const float invN = 1.0f / (float)N_NODES;
        float m = statsIn[tid] * invN;
        float var = statsIn[128 + tid] * invN - m * m;
        float s = g[tid] * rsqrtf(var + BN_EPS);
        abn[tid] = s;
        shbn[tid] = beta[tid] - s * m;
    }
    __syncthreads();

#pragma unroll
    for (int it = 0; it < 2; ++it) {
        int c = tid + it * 512;
        int r = c >> 4, kc = c & 15;
        bf16x8 o = {0, 0, 0, 0, 0, 0, 0, 0};
        if (row0 + r < nrows) {     // pad rows stay exact 0
            bf16x8 v = *(const bf16x8*)(Zin + (size_t)(row0 + r) * DIM + kc * 8);
#pragma unroll
            for (int cc = 0; cc < 8; ++cc) {
                int col = kc * 8 + cc;
                float f = bf2f((unsigned short)v[cc]);
                f = fmaxf(fmaf(abn[col], f, shbn[col]), 0.f);
                o[cc] = (short)f2bf(f);
            }
        }
        *(bf16x8*)&As[r][kc * 8] = o;
    }
    __syncthreads();
    gemm_core8(As, Wt, Zout, statsOut, statsOut + 128, nrows, row0, tid);
}

// ---------------- bnpool: BN2+ReLU apply + h write + fused graph sum-pool ----------------

__global__ __launch_bounds__(256) void bnpool_kernel(
    const unsigned short* __restrict__ Zin, const float* __restrict__ stats,
    const float* __restrict__ g, const float* __restrict__ beta,
    const int* __restrict__ gid, unsigned short* __restrict__ hout,
    float* __restrict__ pooled, int nrows)
{
    __shared__ float abn[DIM], shbn[DIM];
    int tid = threadIdx.x;
    if (tid < DIM) {
        const float invN = 1.0f / (float)N_NODES;
        float m = stats[tid] * invN;
        float var = stats[128 + tid] * invN - m * m;
        float s = g[tid] * rsqrtf(var + BN_EPS);
        abn[tid] = s;
        shbn[tid] = beta[tid] - s * m;
    }
    __syncthreads();

    int row0 = blockIdx.x * GEMM_BM;
    int lane = tid & 63, w = tid >> 6;
    int c0 = lane * 2;
    float a0 = abn[c0], a1 = abn[c0 + 1], s0 = shbn[c0], s1 = shbn[c0 + 1];
    const unsigned int* Z2 = (const unsigned int*)Zin;
    unsigned int* H2 = (unsigned int*)hout;

    float px = 0.f, py = 0.f;
    int gcur = -1;
    for (int i = 0; i < 16; ++i) {
        int r = row0 + w * 16 + i;
        if (r >= nrows) break;
        int gg = gid[r];
        if (gg != gcur) {
            if (gcur >= 0) {
                atomicAdd(&pooled[(size_t)gcur * DIM + c0], px);
                atomicAdd(&pooled[(size_t)gcur * DIM + c0 + 1], py);
            }
            gcur = gg; px = 0.f; py = 0.f;
        }
        unsigned int v = Z2[(size_t)r * 64 + lane];
        float f0 = fmaxf(fmaf(a0, lo16(v), s0), 0.f);
        float f1 = fmaxf(fmaf(a1, hi16(v), s1), 0.f);
        unsigned int o = pack16(f0, f1);
        H2[(size_t)r * 64 + lane] = o;
        px += lo16(o);
        py += hi16(o);
    }
    if (gcur >= 0) {
        atomicAdd(&pooled[(size_t)gcur * DIM + c0], px);
        atomicAdd(&pooled[(size_t)gcur * DIM + c0 + 1], py);
    }
}

// ---------------- graph sum-pool for layer 0 (exact fp32 x) ----------------

__global__ __launch_bounds__(256) void pool_kernel(
    const float* __restrict__ h, const int* __restrict__ gptr, float* __restrict__ outp)
{
    __shared__ float red[DIM];
    int g = blockIdx.x;
    int c = threadIdx.x & 127;
    int half = threadIdx.x >> 7;
    int beg = gptr[g], end = gptr[g + 1];
    float acc = 0.f;
    for (int n = beg + half; n < end; n += 2) acc += h[(size_t)n * DIM + c];
    if (half == 1) red[c] = acc;
    __syncthreads();
    if (half == 0) outp[(size_t)g * DIM + c] = acc + red[c];
}

// ---------------- final readout ----------------

__global__ __launch_bounds__(256) void final_kernel(
    const float* __restrict__ pooledH, const float* __restrict__ Wp,
    const float* __restrict__ bp, float* __restrict__ outp)
{
    int t = blockIdx.x * blockDim.x + threadIdx.x;
    if (t >= N_GRAPHS * N_CLASSES) return;
    int g = t >> 4, c = t & 15;
    float acc = 0.f;
    for (int l = 0; l < N_LAYERS; ++l) {
        const float* ph = pooledH + ((size_t)l * N_GRAPHS + g) * DIM;
        const float* w = Wp + (size_t)l * DIM * N_CLASSES + c;
        float a = 0.f;
        for (int k = 0; k < DIM; ++k) a = fmaf(ph[k], w[k * N_CLASSES], a);
        acc += a + bp[l * N_CLASSES + c];
    }
    outp[t] = acc;
}

// ---------------- host launcher ----------------

extern "C" void kernel_launch(void* const* d_in, const int* in_sizes, int n_in,
                              void* d_out, int out_size, void* d_ws, size_t ws_size,
                              hipStream_t stream) {
    const float* x     = (const float*)d_in[0];
    const float* eps   = (const float*)d_in[1];
    const float* W1    = (const float*)d_in[2];
    const float* g1    = (const float*)d_in[4];
    const float* beta1 = (const float*)d_in[5];
    const float* W2    = (const float*)d_in[6];
    const float* g2    = (const float*)d_in[8];
    const float* beta2 = (const float*)d_in[9];
    const float* Wp    = (const float*)d_in[10];
    const float* bp    = (const float*)d_in[11];
    const int*   esrc  = (const int*)d_in[12];
    const int*   edst  = (const int*)d_in[13];
    const int*   gid   = (const int*)d_in[14];
    float* outp = (float*)d_out;

    char* ws = (char*)d_ws;
    size_t off = 0;
    auto alloc = [&](size_t bytes) {
        char* p = ws + off;
        off = (off + bytes + 255) & ~(size_t)255;
        return p;
    };
    unsigned short* xb  = (unsigned short*)alloc((size_t)N_NODES * DIM * 2);
    unsigned short* B0  = (unsigned short*)alloc((size_t)N_NODES * DIM * 2);  // h ping
    unsigned short* B1  = (unsigned short*)alloc((size_t)N_NODES * DIM * 2);  // h pong
    unsigned short* ZB  = (unsigned short*)alloc((size_t)N_NODES * DIM * 2);  // Z1
    unsigned short* Z2B = (unsigned short*)alloc((size_t)N_NODES * DIM * 2);  // Z2
    unsigned short* Wt1 = (unsigned short*)alloc((size_t)(N_LAYERS - 1) * DIM * DIM * 2);
    unsigned short* Wt2 = (unsigned short*)alloc((size_t)(N_LAYERS - 1) * DIM * DIM * 2);
    int*   csr     = (int*)alloc((size_t)N_EDGES * 4);
    int*   deg     = (int*)alloc((N_NODES + 1) * 4);
    int*   rowptr  = (int*)alloc((N_NODES + 1) * 4);
    int*   cursor  = (int*)alloc((N_NODES + 1) * 4);
    int*   part    = (int*)alloc(64 * 4);
    int*   growptr = (int*)alloc(300 * 4);
    float* stats   = (float*)alloc(8 * 256 * 4);   // [2*(L-1)] x {colsum[128], colsumsq[128]}
    float* pooledH = (float*)alloc((size_t)N_LAYERS * N_GRAPHS * DIM * 4);

    hipMemsetAsync(deg, 0, N_NODES * 4, stream);
    hipMemsetAsync(stats, 0, 8 * 256 * 4, stream);
    hipMemsetAsync(pooledH, 0, (size_t)N_LAYERS * N_GRAPHS * DIM * 4, stream);

    const int nsb = (N_NODES + 1023) / 1024;   // 49 scan blocks
    deg_kernel<<<(N_EDGES + 255) / 256, 256, 0, stream>>>(edst, deg, N_EDGES);
    scan_part_kernel<<<nsb, 1024, 0, stream>>>(deg, part, N_NODES);
    scan_mid_kernel<<<1, 64, 0, stream>>>(part, nsb, rowptr, N_NODES);
    scan_final_kernel<<<nsb, 1024, 0, stream>>>(deg, part, rowptr, cursor, N_NODES);
    fill_csr_kernel<<<(N_EDGES + 255) / 256, 256, 0, stream>>>(esrc, edst, cursor, csr, N_EDGES);
    gbound_kernel<<<(N_NODES + 255) / 256, 256, 0, stream>>>(gid, growptr, N_NODES, N_GRAPHS);

    f2b_kernel<<<(N_NODES * DIM / 4 + 255) / 256, 256, 0, stream>>>(x, xb, N_NODES * DIM / 4);
    wconv_kernel<<<((N_LAYERS - 1) * DIM * DIM + 255) / 256, 256, 0, stream>>>(W1, Wt1, N_LAYERS - 1);
    wconv_kernel<<<((N_LAYERS - 1) * DIM * DIM + 255) / 256, 256, 0, stream>>>(W2, Wt2, N_LAYERS - 1);

    pool_kernel<<<N_GRAPHS, 256, 0, stream>>>(x, growptr, pooledH);   // layer 0 exact

    const int ngrid = (N_NODES + GEMM_BM - 1) / GEMM_BM;   // 782
    unsigned short* hb = xb;
    unsigned short* nb = B0;
    for (int l = 0; l < N_LAYERS - 1; ++l) {
        gemmA_kernel<<<ngrid, 512, 0, stream>>>(
            hb, rowptr, csr, eps, l, Wt1 + (size_t)l * DIM * DIM, ZB,
            stats + (size_t)(2 * l) * 256, N_NODES);
        gemmB_kernel<<<ngrid, 512, 0, stream>>>(
            ZB, stats + (size_t)(2 * l) * 256, g1 + l * DIM, beta1 + l * DIM,
            Wt2 + (size_t)l * DIM * DIM, Z2B, stats + (size_t)(2 * l + 1) * 256, N_NODES);
        bnpool_kernel<<<ngrid, 256, 0, stream>>>(
            Z2B, stats + (size_t)(2 * l + 1) * 256, g2 + l * DIM, beta2 + l * DIM,
            gid, nb, pooledH + (size_t)(l + 1) * N_GRAPHS * DIM, N_NODES);

        hb = nb;
        nb = (hb == B0) ? B1 : B0;
    }

    final_kernel<<<(N_GRAPHS * N_CLASSES + 255) / 256, 256, 0, stream>>>(pooledH, Wp, bp, outp);
}